// Round 4
// baseline (273.088 us; speedup 1.0000x reference)
//
#include <hip/hip_runtime.h>
#include <hip/hip_bf16.h>

#define BB 2
#define TT 2048
#define DM 1024
#define NH 16
#define HD 64
#define BT (BB*TT)

typedef unsigned short u16;
typedef __attribute__((ext_vector_type(8))) short short8;
typedef __attribute__((ext_vector_type(4))) float f32x4;

__device__ __forceinline__ u16 f2b(float f){
  unsigned u = __builtin_bit_cast(unsigned, f);
  u += 0x7FFFu + ((u >> 16) & 1u);
  return (u16)(u >> 16);
}
__device__ __forceinline__ float b2f(u16 h){
  unsigned u = ((unsigned)h) << 16;
  return __builtin_bit_cast(float, u);
}

__device__ __forceinline__ void gll16(const u16* g, u16* l){
  __builtin_amdgcn_global_load_lds((const __attribute__((address_space(1))) void*)g,
                                   (__attribute__((address_space(3))) void*)l, 16, 0, 0);
}

// ---------------- f32 -> bf16 conversion (X) ----------------
__global__ __launch_bounds__(256) void cvt_kernel(const float* __restrict__ src,
                                                  u16* __restrict__ dst, int n4){
  int i = blockIdx.x*256 + threadIdx.x;
  if (i < n4){
    const float4 v = *(const float4*)(src + (size_t)i*4);
    ushort4 o;
    o.x = f2b(v.x); o.y = f2b(v.y); o.z = f2b(v.z); o.w = f2b(v.w);
    *(ushort4*)(dst + (size_t)i*4) = o;
  }
}

// ---------------- fused weight conversion (4 x 1M elems) ----------------
__global__ __launch_bounds__(256) void cvt_w_kernel(const float* __restrict__ w0,
                                                    const float* __restrict__ w1,
                                                    const float* __restrict__ w2,
                                                    const float* __restrict__ w3,
                                                    u16* __restrict__ dst){
  const int seg = blockIdx.x >> 10;
  const int i = (blockIdx.x & 1023)*256 + threadIdx.x;
  const float* src = (seg==0)?w0:(seg==1)?w1:(seg==2)?w2:w3;
  const float4 v = *(const float4*)(src + (size_t)i*4);
  ushort4 o;
  o.x = f2b(v.x); o.y = f2b(v.y); o.z = f2b(v.z); o.w = f2b(v.w);
  *(ushort4*)(dst + (size_t)seg*DM*DM + (size_t)i*4) = o;
}

// ---------------- 128x128-tile LDS-staged GEMM ----------------
#define FRAG(buf, row) (*(const short8*)((buf) + (size_t)(row)*32 + ((g ^ (((row)>>1)&3))*8)))

template<int MODE>
__global__ __launch_bounds__(256) void gemm128(const u16* __restrict__ A,
                                               const u16* __restrict__ W,
                                               u16* __restrict__ Ybf,
                                               float* __restrict__ Yf){
  __shared__ u16 sA0[4096], sB0[4096], sA1[4096], sB1[4096];
  const int tid = threadIdx.x;
  const int lane = tid & 63;
  const int wave = tid >> 6;
  const int r = lane & 15, g = lane >> 4;
  const int wr = wave >> 1, wc = wave & 1;
  const int m0 = blockIdx.y << 7;
  const int nn0 = blockIdx.x << 7;

  const int srow = tid >> 2;
  const int lcol = (((tid & 3) ^ ((srow >> 1) & 3))) * 8;

  const u16* gA0 = A + (size_t)(m0 + srow)*DM + lcol;
  const u16* gA1 = gA0 + (size_t)64*DM;
  const u16* gB0 = W + (size_t)(nn0 + srow)*DM + lcol;
  const u16* gB1 = gB0 + (size_t)64*DM;

  f32x4 acc[4][4];
  #pragma unroll
  for (int i=0;i<4;i++)
    #pragma unroll
    for (int j=0;j<4;j++) acc[i][j] = (f32x4){0.f,0.f,0.f,0.f};

#define STAGE(SA, SB, koff) { \
    gll16(gA0 + (koff), SA + (size_t)tid*8); \
    gll16(gA1 + (koff), SA + 2048 + (size_t)tid*8); \
    gll16(gB0 + (koff), SB + (size_t)tid*8); \
    gll16(gB1 + (koff), SB + 2048 + (size_t)tid*8); }

#define COMPUTE(SA, SB) { \
    short8 af[4], bf[4]; \
    _Pragma("unroll") \
    for (int f=0; f<4; f++){ \
      af[f] = FRAG(SA, wr*64 + f*16 + r); \
      bf[f] = FRAG(SB, wc*64 + f*16 + r); \
    } \
    _Pragma("unroll") \
    for (int fr=0; fr<4; fr++) \
      _Pragma("unroll") \
      for (int fn=0; fn<4; fn++) \
        acc[fr][fn] = __builtin_amdgcn_mfma_f32_16x16x32_bf16(af[fr], bf[fn], acc[fr][fn], 0,0,0); }

  STAGE(sA0, sB0, 0);
  __syncthreads();

  for (int t = 0; t < 32; t += 2){
    if (t + 1 < 32) STAGE(sA1, sB1, (t+1)*32);
    COMPUTE(sA0, sB0);
    __syncthreads();
    if (t + 2 < 32) STAGE(sA0, sB0, (t+2)*32);
    COMPUTE(sA1, sB1);
    __syncthreads();
  }

  #pragma unroll
  for (int fr=0; fr<4; fr++){
    #pragma unroll
    for (int i=0;i<4;i++){
      const int m = m0 + wr*64 + fr*16 + g*4 + i;
      #pragma unroll
      for (int fn=0; fn<4; fn++){
        const int nn = nn0 + wc*64 + fn*16 + r;
        if (MODE == 0){
          Ybf[(size_t)(nn >> 10)*BT*DM + (size_t)m*DM + (nn & 1023)] = f2b(acc[fr][fn][i]);
        } else {
          Yf[(size_t)m*DM + nn] = acc[fr][fn][i];
        }
      }
    }
  }
#undef STAGE
#undef COMPUTE
}

// ---------------- RoPE on Q,K ----------------
__global__ __launch_bounds__(256) void rope_kernel(u16* __restrict__ Qb, u16* __restrict__ Kb,
                                                   const int* __restrict__ pos){
  const int t = blockIdx.x*256 + threadIdx.x;
  const int m = t >> 5;
  const int fi = t & 31;
  const float invf = __expf(-(float)fi * 0.28782313662425575f);
  float s, c;
  sincosf((float)pos[m] * invf, &s, &c);
  const size_t base = (size_t)m*DM + fi*2;
  #pragma unroll
  for (int h=0; h<NH; h++){
    const size_t a = base + h*HD;
    {
      const float x0 = b2f(Qb[a]), x1 = b2f(Qb[a+1]);
      Qb[a]   = f2b(c*x0 - s*x1);
      Qb[a+1] = f2b(c*x1 + s*x0);
    }
    {
      const float x0 = b2f(Kb[a]), x1 = b2f(Kb[a+1]);
      Kb[a]   = f2b(c*x0 - s*x1);
      Kb[a+1] = f2b(c*x1 + s*x0);
    }
  }
}

// ---------------- V transpose ----------------
__global__ __launch_bounds__(256) void transpose_v_kernel(const u16* __restrict__ Vb,
                                                          u16* __restrict__ Vt){
  __shared__ u16 tile[64][72];
  const int bh = blockIdx.x >> 5;
  const int sc = blockIdx.x & 31;
  const int bq = bh >> 4, h = bh & 15;
  const int s0 = sc*64;
  {
    const int row = threadIdx.x >> 3;
    const int c8 = (threadIdx.x & 7)*8;
    #pragma unroll
    for (int rr = 0; rr < 64; rr += 32){
      const short8 v = *(const short8*)(Vb + (size_t)(bq*TT + s0 + row + rr)*DM + h*HD + c8);
      *(short8*)(&tile[row+rr][c8]) = v;
    }
  }
  __syncthreads();
  {
    const int d = threadIdx.x >> 3;
    const int s8 = (threadIdx.x & 7)*8;
    #pragma unroll
    for (int dd = 0; dd < 64; dd += 32){
      short8 ov;
      #pragma unroll
      for (int j=0;j<8;j++) ov[j] = (short)tile[s8+j][d+dd];
      *(short8*)(Vt + ((size_t)bh*HD + d + dd)*TT + s0 + s8) = ov;
    }
  }
}

// ---------------- causal flash attention (split-K parity, defer-max) ----------------
// log2-domain: scores scaled by 0.125/ln2; exp2f everywhere.
#define SC2 0.18033688011112042f
#define THR2 11.541560327111707f

template<bool MASKED>
__device__ __forceinline__ void proc_tile2(
    const short8 qf0, const short8 qf1,
    const short8 k00, const short8 k01, const short8 k10, const short8 k11,
    const short8 v0, const short8 v1, const short8 v2, const short8 v3,
    f32x4& o0, f32x4& o1, f32x4& o2, f32x4& o3,
    float (&mrow)[4], float (&lsum)[4],
    const int q0, const int s0, const int r, const int g,
    u16 (*pbuf)[40])
{
  f32x4 sa0={0,0,0,0}, sa1={0,0,0,0};
  sa0 = __builtin_amdgcn_mfma_f32_16x16x32_bf16(qf0, k00, sa0, 0,0,0);
  sa0 = __builtin_amdgcn_mfma_f32_16x16x32_bf16(qf1, k01, sa0, 0,0,0);
  sa1 = __builtin_amdgcn_mfma_f32_16x16x32_bf16(qf0, k10, sa1, 0,0,0);
  sa1 = __builtin_amdgcn_mfma_f32_16x16x32_bf16(qf1, k11, sa1, 0,0,0);

  float sv0[4], sv1[4], lm[4];
  bool ok = true;
  #pragma unroll
  for (int i=0;i<4;i++){
    if (MASKED){
      const int q = q0 + g*4 + i;
      sv0[i] = (s0 + r      <= q) ? sa0[i]*SC2 : -3.0e38f;
      sv1[i] = (s0 + 16 + r <= q) ? sa1[i]*SC2 : -3.0e38f;
    } else {
      sv0[i] = sa0[i]*SC2;
      sv1[i] = sa1[i]*SC2;
    }
    lm[i] = fmaxf(sv0[i], sv1[i]);
    ok = ok && (lm[i] <= mrow[i] + THR2);
  }
  if (!__all((int)ok)){
    float pm[4];
    #pragma unroll
    for (int i=0;i<4;i++) pm[i] = lm[i];
    #pragma unroll
    for (int off=8; off>0; off>>=1){
      #pragma unroll
      for (int i=0;i<4;i++) pm[i] = fmaxf(pm[i], __shfl_xor(pm[i], off));
    }
    #pragma unroll
    for (int i=0;i<4;i++){
      const float mn = fmaxf(mrow[i], pm[i]);
      const float corr = exp2f(mrow[i] - mn);
      mrow[i] = mn;
      lsum[i] *= corr;
      o0[i] *= corr; o1[i] *= corr; o2[i] *= corr; o3[i] *= corr;
    }
  }
  #pragma unroll
  for (int i=0;i<4;i++){
    const float p0 = exp2f(sv0[i] - mrow[i]);
    const float p1 = exp2f(sv1[i] - mrow[i]);
    lsum[i] += p0 + p1;
    pbuf[g*4+i][r]      = f2b(p0);
    pbuf[g*4+i][16 + r] = f2b(p1);
  }
  const short8 pf = *(const short8*)(&pbuf[r][g*8]);
  o0 = __builtin_amdgcn_mfma_f32_16x16x32_bf16(pf, v0, o0, 0,0,0);
  o1 = __builtin_amdgcn_mfma_f32_16x16x32_bf16(pf, v1, o1, 0,0,0);
  o2 = __builtin_amdgcn_mfma_f32_16x16x32_bf16(pf, v2, o2, 0,0,0);
  o3 = __builtin_amdgcn_mfma_f32_16x16x32_bf16(pf, v3, o3, 0,0,0);
}

__global__ __launch_bounds__(256) void attn_kernel(const u16* __restrict__ Qb,
                                                   const u16* __restrict__ Kb,
                                                   const u16* __restrict__ Vt,
                                                   u16* __restrict__ Ob){
  __shared__ u16 Plds[4][16][40];
  __shared__ float Mbuf[2][24][64];   // [pair][component][lane]
  const int lane = threadIdx.x & 63;
  const int wave = threadIdx.x >> 6;
  const int wg = blockIdx.x*4 + wave;   // 0..8191
  const int p  = wg & 1;
  const int qt = (wg >> 1) & 127;
  const int bh = wg >> 8;               // 0..31
  const int bq = bh >> 4;
  const int h = bh & 15;
  const int q0 = qt << 4;
  const int r = lane & 15, g = lane >> 4;
  const int pair = wave >> 1;

  const u16* Qrow = Qb + (size_t)(bq*TT + q0 + r)*DM + h*HD;
  const short8 qf0 = *(const short8*)(Qrow + g*8);
  const short8 qf1 = *(const short8*)(Qrow + 32 + g*8);

  f32x4 o0={0,0,0,0}, o1={0,0,0,0}, o2={0,0,0,0}, o3={0,0,0,0};
  float mrow[4], lsum[4];
  #pragma unroll
  for (int i=0;i<4;i++){ mrow[i] = 0.f; lsum[i] = 0.f; }

  const int nb = ((q0 + 15) >> 5) + 1;
  const int nf = (q0 + 1) >> 5;        // blocks < nf need no mask
  const u16* Kbase = Kb + (size_t)(bq*TT)*DM + h*HD;
  const u16* Vtb = Vt + (size_t)bh*HD*TT;

  // prefetch K for first block (ib = p); always in-bounds (row <= 63)
  short8 kc00, kc01, kc10, kc11;
  {
    const u16* Kr0 = Kbase + (size_t)(p*32 + r)*DM;
    const u16* Kr1 = Kr0 + (size_t)16*DM;
    kc00 = *(const short8*)(Kr0 + g*8);
    kc01 = *(const short8*)(Kr0 + 32 + g*8);
    kc10 = *(const short8*)(Kr1 + g*8);
    kc11 = *(const short8*)(Kr1 + 32 + g*8);
  }

  for (int ib = p; ib < nb; ib += 2){
    const int s0 = ib << 5;
    // V for current block (latency hides under QK^T + softmax)
    const u16* Vr = Vtb + (size_t)r*TT + s0 + g*8;
    const short8 v0 = *(const short8*)(Vr);
    const short8 v1 = *(const short8*)(Vr + (size_t)16*TT);
    const short8 v2 = *(const short8*)(Vr + (size_t)32*TT);
    const short8 v3 = *(const short8*)(Vr + (size_t)48*TT);
    // prefetch K for next block (ib+2)
    short8 kn00=kc00, kn01=kc01, kn10=kc10, kn11=kc11;
    if (ib + 2 < nb){
      const u16* Kr0 = Kbase + (size_t)(s0 + 64 + r)*DM;
      const u16* Kr1 = Kr0 + (size_t)16*DM;
      kn00 = *(const short8*)(Kr0 + g*8);
      kn01 = *(const short8*)(Kr0 + 32 + g*8);
      kn10 = *(const short8*)(Kr1 + g*8);
      kn11 = *(const short8*)(Kr1 + 32 + g*8);
    }
    if (ib < nf){
      proc_tile2<false>(qf0,qf1,kc00,kc01,kc10,kc11,v0,v1,v2,v3,
                        o0,o1,o2,o3,mrow,lsum,q0,s0,r,g,Plds[wave]);
    } else {
      proc_tile2<true >(qf0,qf1,kc00,kc01,kc10,kc11,v0,v1,v2,v3,
                        o0,o1,o2,o3,mrow,lsum,q0,s0,r,g,Plds[wave]);
    }
    kc00=kn00; kc01=kn01; kc10=kn10; kc11=kn11;
  }

  // parity-1 wave publishes its partial state
  if (p == 1){
    float* b = &Mbuf[pair][0][0];
    #pragma unroll
    for (int i=0;i<4;i++){
      b[(0*4+i)*64 + lane] = o0[i];
      b[(1*4+i)*64 + lane] = o1[i];
      b[(2*4+i)*64 + lane] = o2[i];
      b[(3*4+i)*64 + lane] = o3[i];
      b[(16+i)*64 + lane] = mrow[i];
      b[(20+i)*64 + lane] = lsum[i];
    }
  }
  __syncthreads();
  if (p == 0){
    const float* b = &Mbuf[pair][0][0];
    float c0[4], c1[4];
    #pragma unroll
    for (int i=0;i<4;i++){
      const float m1 = b[(16+i)*64 + lane];
      const float l1 = b[(20+i)*64 + lane];
      const float m  = fmaxf(mrow[i], m1);
      c0[i] = exp2f(mrow[i] - m);
      c1[i] = exp2f(m1 - m);
      lsum[i] = lsum[i]*c0[i] + l1*c1[i];
    }
    #pragma unroll
    for (int i=0;i<4;i++){
      o0[i] = o0[i]*c0[i] + b[(0*4+i)*64 + lane]*c1[i];
      o1[i] = o1[i]*c0[i] + b[(1*4+i)*64 + lane]*c1[i];
      o2[i] = o2[i]*c0[i] + b[(2*4+i)*64 + lane]*c1[i];
      o3[i] = o3[i]*c0[i] + b[(3*4+i)*64 + lane]*c1[i];
    }
    #pragma unroll
    for (int off=8; off>0; off>>=1){
      #pragma unroll
      for (int i=0;i<4;i++) lsum[i] += __shfl_xor(lsum[i], off);
    }
    float inv[4];
    #pragma unroll
    for (int i=0;i<4;i++) inv[i] = 1.0f / lsum[i];
    #pragma unroll
    for (int i=0;i<4;i++){
      const size_t row = (size_t)(bq*TT + q0 + g*4 + i)*DM + h*HD;
      Ob[row + r]      = f2b(o0[i]*inv[i]);
      Ob[row + 16 + r] = f2b(o1[i]*inv[i]);
      Ob[row + 32 + r] = f2b(o2[i]*inv[i]);
      Ob[row + 48 + r] = f2b(o3[i]*inv[i]);
    }
  }
}

extern "C" void kernel_launch(void* const* d_in, const int* in_sizes, int n_in,
                              void* d_out, int out_size, void* d_ws, size_t ws_size,
                              hipStream_t stream) {
  const float* X  = (const float*)d_in[0];
  const int* pos  = (const int*)d_in[1];
  const float* Wq = (const float*)d_in[2];
  const float* Wk = (const float*)d_in[3];
  const float* Wv = (const float*)d_in[4];
  const float* Wo = (const float*)d_in[5];
  float* out = (float*)d_out;

  char* ws = (char*)d_ws;
  u16* Xb = (u16*)ws;                                    // 8 MB (reused as Vt later)
  u16* Vt = (u16*)ws;                                    // aliases Xb (dead after QKV gemm)
  u16* Wb = (u16*)(ws + (size_t)8*1024*1024);            // 4 x 2 MB (q,k,v,o)
  u16* Qb = (u16*)(ws + (size_t)16*1024*1024);           // 8 MB
  u16* Kb = Qb + (size_t)BT*DM;                          // 8 MB
  u16* Vb = Kb + (size_t)BT*DM;                          // 8 MB
  u16* Ob = (u16*)(ws + (size_t)40*1024*1024);           // 8 MB

  const int DD = DM*DM;
  cvt_kernel<<<4096, 256, 0, stream>>>(X, Xb, BT*DM/4);
  cvt_w_kernel<<<4096, 256, 0, stream>>>(Wq, Wk, Wv, Wo, Wb);

  gemm128<0><<<dim3(24, 32), 256, 0, stream>>>(Xb, Wb, Qb, nullptr);
  rope_kernel<<<512, 256, 0, stream>>>(Qb, Kb, pos);
  transpose_v_kernel<<<1024, 256, 0, stream>>>(Vb, Vt);
  attn_kernel<<<2048, 256, 0, stream>>>(Qb, Kb, Vt, Ob);
  gemm128<1><<<dim3(8, 32), 256, 0, stream>>>(Ob, Wb + 3*DD, nullptr, out);
}

// Round 5
// 199.573 us; speedup vs baseline: 1.3684x; 1.3684x over previous
//
#include <hip/hip_runtime.h>
#include <hip/hip_bf16.h>

#define BB 2
#define TT 2048
#define DM 1024
#define NH 16
#define HD 64
#define BT (BB*TT)

typedef unsigned short u16;
typedef __attribute__((ext_vector_type(8))) short short8;
typedef __attribute__((ext_vector_type(4))) float f32x4;

__device__ __forceinline__ u16 f2b(float f){
  unsigned u = __builtin_bit_cast(unsigned, f);
  u += 0x7FFFu + ((u >> 16) & 1u);
  return (u16)(u >> 16);
}
__device__ __forceinline__ float b2f(u16 h){
  unsigned u = ((unsigned)h) << 16;
  return __builtin_bit_cast(float, u);
}

__device__ __forceinline__ void gll16(const u16* g, u16* l){
  __builtin_amdgcn_global_load_lds((const __attribute__((address_space(1))) void*)g,
                                   (__attribute__((address_space(3))) void*)l, 16, 0, 0);
}

// ---------------- f32 -> bf16 conversion (X) ----------------
__global__ __launch_bounds__(256) void cvt_kernel(const float* __restrict__ src,
                                                  u16* __restrict__ dst, int n4){
  int i = blockIdx.x*256 + threadIdx.x;
  if (i < n4){
    const float4 v = *(const float4*)(src + (size_t)i*4);
    ushort4 o;
    o.x = f2b(v.x); o.y = f2b(v.y); o.z = f2b(v.z); o.w = f2b(v.w);
    *(ushort4*)(dst + (size_t)i*4) = o;
  }
}

// ---------------- fused weight conversion (4 x 1M elems) ----------------
__global__ __launch_bounds__(256) void cvt_w_kernel(const float* __restrict__ w0,
                                                    const float* __restrict__ w1,
                                                    const float* __restrict__ w2,
                                                    const float* __restrict__ w3,
                                                    u16* __restrict__ dst){
  const int seg = blockIdx.x >> 10;
  const int i = (blockIdx.x & 1023)*256 + threadIdx.x;
  const float* src = (seg==0)?w0:(seg==1)?w1:(seg==2)?w2:w3;
  const float4 v = *(const float4*)(src + (size_t)i*4);
  ushort4 o;
  o.x = f2b(v.x); o.y = f2b(v.y); o.z = f2b(v.z); o.w = f2b(v.w);
  *(ushort4*)(dst + (size_t)seg*DM*DM + (size_t)i*4) = o;
}

// ---------------- 128x128-tile LDS-staged GEMM ----------------
#define FRAG(buf, row) (*(const short8*)((buf) + (size_t)(row)*32 + ((g ^ (((row)>>1)&3))*8)))

template<int MODE>
__global__ __launch_bounds__(256) void gemm128(const u16* __restrict__ A,
                                               const u16* __restrict__ W,
                                               u16* __restrict__ Ybf,
                                               float* __restrict__ Yf){
  __shared__ u16 sA0[4096], sB0[4096], sA1[4096], sB1[4096];
  const int tid = threadIdx.x;
  const int lane = tid & 63;
  const int wave = tid >> 6;
  const int r = lane & 15, g = lane >> 4;
  const int wr = wave >> 1, wc = wave & 1;
  const int m0 = blockIdx.y << 7;
  const int nn0 = blockIdx.x << 7;

  const int srow = tid >> 2;
  const int lcol = (((tid & 3) ^ ((srow >> 1) & 3))) * 8;

  const u16* gA0 = A + (size_t)(m0 + srow)*DM + lcol;
  const u16* gA1 = gA0 + (size_t)64*DM;
  const u16* gB0 = W + (size_t)(nn0 + srow)*DM + lcol;
  const u16* gB1 = gB0 + (size_t)64*DM;

  f32x4 acc[4][4];
  #pragma unroll
  for (int i=0;i<4;i++)
    #pragma unroll
    for (int j=0;j<4;j++) acc[i][j] = (f32x4){0.f,0.f,0.f,0.f};

#define STAGE(SA, SB, koff) { \
    gll16(gA0 + (koff), SA + (size_t)tid*8); \
    gll16(gA1 + (koff), SA + 2048 + (size_t)tid*8); \
    gll16(gB0 + (koff), SB + (size_t)tid*8); \
    gll16(gB1 + (koff), SB + 2048 + (size_t)tid*8); }

#define COMPUTE(SA, SB) { \
    short8 af[4], bf[4]; \
    _Pragma("unroll") \
    for (int f=0; f<4; f++){ \
      af[f] = FRAG(SA, wr*64 + f*16 + r); \
      bf[f] = FRAG(SB, wc*64 + f*16 + r); \
    } \
    _Pragma("unroll") \
    for (int fr=0; fr<4; fr++) \
      _Pragma("unroll") \
      for (int fn=0; fn<4; fn++) \
        acc[fr][fn] = __builtin_amdgcn_mfma_f32_16x16x32_bf16(af[fr], bf[fn], acc[fr][fn], 0,0,0); }

  STAGE(sA0, sB0, 0);
  __syncthreads();

  for (int t = 0; t < 32; t += 2){
    if (t + 1 < 32) STAGE(sA1, sB1, (t+1)*32);
    COMPUTE(sA0, sB0);
    __syncthreads();
    if (t + 2 < 32) STAGE(sA0, sB0, (t+2)*32);
    COMPUTE(sA1, sB1);
    __syncthreads();
  }

  #pragma unroll
  for (int fr=0; fr<4; fr++){
    #pragma unroll
    for (int i=0;i<4;i++){
      const int m = m0 + wr*64 + fr*16 + g*4 + i;
      #pragma unroll
      for (int fn=0; fn<4; fn++){
        const int nn = nn0 + wc*64 + fn*16 + r;
        if (MODE == 0){
          Ybf[(size_t)(nn >> 10)*BT*DM + (size_t)m*DM + (nn & 1023)] = f2b(acc[fr][fn][i]);
        } else {
          Yf[(size_t)m*DM + nn] = acc[fr][fn][i];
        }
      }
    }
  }
#undef STAGE
#undef COMPUTE
}

// ---------------- RoPE on Q,K ----------------
__global__ __launch_bounds__(256) void rope_kernel(u16* __restrict__ Qb, u16* __restrict__ Kb,
                                                   const int* __restrict__ pos){
  const int t = blockIdx.x*256 + threadIdx.x;
  const int m = t >> 5;
  const int fi = t & 31;
  const float invf = __expf(-(float)fi * 0.28782313662425575f);
  float s, c;
  sincosf((float)pos[m] * invf, &s, &c);
  const size_t base = (size_t)m*DM + fi*2;
  #pragma unroll
  for (int h=0; h<NH; h++){
    const size_t a = base + h*HD;
    {
      const float x0 = b2f(Qb[a]), x1 = b2f(Qb[a+1]);
      Qb[a]   = f2b(c*x0 - s*x1);
      Qb[a+1] = f2b(c*x1 + s*x0);
    }
    {
      const float x0 = b2f(Kb[a]), x1 = b2f(Kb[a+1]);
      Kb[a]   = f2b(c*x0 - s*x1);
      Kb[a+1] = f2b(c*x1 + s*x0);
    }
  }
}

// ---------------- V transpose ----------------
__global__ __launch_bounds__(256) void transpose_v_kernel(const u16* __restrict__ Vb,
                                                          u16* __restrict__ Vt){
  __shared__ u16 tile[64][72];
  const int bh = blockIdx.x >> 5;
  const int sc = blockIdx.x & 31;
  const int bq = bh >> 4, h = bh & 15;
  const int s0 = sc*64;
  {
    const int row = threadIdx.x >> 3;
    const int c8 = (threadIdx.x & 7)*8;
    #pragma unroll
    for (int rr = 0; rr < 64; rr += 32){
      const short8 v = *(const short8*)(Vb + (size_t)(bq*TT + s0 + row + rr)*DM + h*HD + c8);
      *(short8*)(&tile[row+rr][c8]) = v;
    }
  }
  __syncthreads();
  {
    const int d = threadIdx.x >> 3;
    const int s8 = (threadIdx.x & 7)*8;
    #pragma unroll
    for (int dd = 0; dd < 64; dd += 32){
      short8 ov;
      #pragma unroll
      for (int j=0;j<8;j++) ov[j] = (short)tile[s8+j][d+dd];
      *(short8*)(Vt + ((size_t)bh*HD + d + dd)*TT + s0 + s8) = ov;
    }
  }
}

// ---------- causal flash attention: paired q-tiles + parity split-K ----------
// log2-domain: scores scaled by 0.125/ln2; exp2f everywhere. defer-max (T13).
#define SC2 0.18033688011112042f
#define THR2 11.541560327111707f

template<bool MASKED>
__device__ __forceinline__ void proc_tile3(
    const short8 qf0, const short8 qf1,
    const short8 k00, const short8 k01, const short8 k10, const short8 k11,
    const short8 v0, const short8 v1, const short8 v2, const short8 v3,
    f32x4& o0, f32x4& o1, f32x4& o2, f32x4& o3,
    float (&mrow)[4], float (&lsum)[4],
    const int q0, const int s0, const int r, const int g,
    u16 (*pbuf)[40])
{
  f32x4 sa0={0,0,0,0}, sa1={0,0,0,0};
  sa0 = __builtin_amdgcn_mfma_f32_16x16x32_bf16(qf0, k00, sa0, 0,0,0);
  sa0 = __builtin_amdgcn_mfma_f32_16x16x32_bf16(qf1, k01, sa0, 0,0,0);
  sa1 = __builtin_amdgcn_mfma_f32_16x16x32_bf16(qf0, k10, sa1, 0,0,0);
  sa1 = __builtin_amdgcn_mfma_f32_16x16x32_bf16(qf1, k11, sa1, 0,0,0);

  float sv0[4], sv1[4], lm[4];
  bool ok = true;
  #pragma unroll
  for (int i=0;i<4;i++){
    if (MASKED){
      const int q = q0 + g*4 + i;
      sv0[i] = (s0 + r      <= q) ? sa0[i]*SC2 : -3.0e38f;
      sv1[i] = (s0 + 16 + r <= q) ? sa1[i]*SC2 : -3.0e38f;
    } else {
      sv0[i] = sa0[i]*SC2;
      sv1[i] = sa1[i]*SC2;
    }
    lm[i] = fmaxf(sv0[i], sv1[i]);
    ok = ok && (lm[i] <= mrow[i] + THR2);
  }
  if (!__all((int)ok)){
    float pm[4];
    #pragma unroll
    for (int i=0;i<4;i++) pm[i] = lm[i];
    #pragma unroll
    for (int off=8; off>0; off>>=1){
      #pragma unroll
      for (int i=0;i<4;i++) pm[i] = fmaxf(pm[i], __shfl_xor(pm[i], off));
    }
    #pragma unroll
    for (int i=0;i<4;i++){
      const float mn = fmaxf(mrow[i], pm[i]);
      const float corr = exp2f(mrow[i] - mn);
      mrow[i] = mn;
      lsum[i] *= corr;
      o0[i] *= corr; o1[i] *= corr; o2[i] *= corr; o3[i] *= corr;
    }
  }
  #pragma unroll
  for (int i=0;i<4;i++){
    const float p0 = exp2f(sv0[i] - mrow[i]);
    const float p1 = exp2f(sv1[i] - mrow[i]);
    lsum[i] += p0 + p1;
    pbuf[g*4+i][r]      = f2b(p0);
    pbuf[g*4+i][16 + r] = f2b(p1);
  }
  const short8 pf = *(const short8*)(&pbuf[r][g*8]);
  o0 = __builtin_amdgcn_mfma_f32_16x16x32_bf16(pf, v0, o0, 0,0,0);
  o1 = __builtin_amdgcn_mfma_f32_16x16x32_bf16(pf, v1, o1, 0,0,0);
  o2 = __builtin_amdgcn_mfma_f32_16x16x32_bf16(pf, v2, o2, 0,0,0);
  o3 = __builtin_amdgcn_mfma_f32_16x16x32_bf16(pf, v3, o3, 0,0,0);
}

__global__ __launch_bounds__(256) void attn_kernel(const u16* __restrict__ Qb,
                                                   const u16* __restrict__ Kb,
                                                   const u16* __restrict__ Vt,
                                                   u16* __restrict__ Ob){
  __shared__ u16 Plds[4][2][16][40];       // [wave][tile][row][col]
  __shared__ float Mbuf[2][2][24][64];     // [pair][tile][comp][lane]
  const int lane = threadIdx.x & 63;
  const int wave = threadIdx.x >> 6;
  const int wg = blockIdx.x*4 + wave;   // 0..4095
  const int p  = wg & 1;
  const int qt = (wg >> 1) & 63;        // pair id
  const int bh = wg >> 7;               // 0..31
  const int bq = bh >> 4;
  const int h = bh & 15;
  const int qlo = qt << 4;
  const int qhi = (127 - qt) << 4;
  const int r = lane & 15, g = lane >> 4;
  const int pair = wave >> 1;

  const u16* QrowL = Qb + (size_t)(bq*TT + qlo + r)*DM + h*HD;
  const u16* QrowH = Qb + (size_t)(bq*TT + qhi + r)*DM + h*HD;
  const short8 qL0 = *(const short8*)(QrowL + g*8);
  const short8 qL1 = *(const short8*)(QrowL + 32 + g*8);
  const short8 qH0 = *(const short8*)(QrowH + g*8);
  const short8 qH1 = *(const short8*)(QrowH + 32 + g*8);

  f32x4 oL0={0,0,0,0}, oL1={0,0,0,0}, oL2={0,0,0,0}, oL3={0,0,0,0};
  f32x4 oH0={0,0,0,0}, oH1={0,0,0,0}, oH2={0,0,0,0}, oH3={0,0,0,0};
  float mL[4], lL[4], mH[4], lH[4];
  #pragma unroll
  for (int i=0;i<4;i++){ mL[i]=0.f; lL[i]=0.f; mH[i]=0.f; lH[i]=0.f; }

  const int nbL = ((qlo + 15) >> 5) + 1;
  const int nbH = ((qhi + 15) >> 5) + 1;
  const int nfL = (qlo + 1) >> 5;
  const int nfH = (qhi + 1) >> 5;
  const u16* Kbase = Kb + (size_t)(bq*TT)*DM + h*HD;
  const u16* Vtb = Vt + (size_t)bh*HD*TT;

  // prefetch K for first block (ib = p)
  short8 kc00, kc01, kc10, kc11;
  {
    const u16* Kr0 = Kbase + (size_t)(p*32 + r)*DM;
    const u16* Kr1 = Kr0 + (size_t)16*DM;
    kc00 = *(const short8*)(Kr0 + g*8);
    kc01 = *(const short8*)(Kr0 + 32 + g*8);
    kc10 = *(const short8*)(Kr1 + g*8);
    kc11 = *(const short8*)(Kr1 + 32 + g*8);
  }

  for (int ib = p; ib < nbH; ib += 2){
    const int s0 = ib << 5;
    const u16* Vr = Vtb + (size_t)r*TT + s0 + g*8;
    const short8 v0 = *(const short8*)(Vr);
    const short8 v1 = *(const short8*)(Vr + (size_t)16*TT);
    const short8 v2 = *(const short8*)(Vr + (size_t)32*TT);
    const short8 v3 = *(const short8*)(Vr + (size_t)48*TT);
    short8 kn00=kc00, kn01=kc01, kn10=kc10, kn11=kc11;
    if (ib + 2 < nbH){
      const u16* Kr0 = Kbase + (size_t)(s0 + 64 + r)*DM;
      const u16* Kr1 = Kr0 + (size_t)16*DM;
      kn00 = *(const short8*)(Kr0 + g*8);
      kn01 = *(const short8*)(Kr0 + 32 + g*8);
      kn10 = *(const short8*)(Kr1 + g*8);
      kn11 = *(const short8*)(Kr1 + 32 + g*8);
    }
    if (ib < nfH){
      proc_tile3<false>(qH0,qH1,kc00,kc01,kc10,kc11,v0,v1,v2,v3,
                        oH0,oH1,oH2,oH3,mH,lH,qhi,s0,r,g,Plds[wave][0]);
    } else {
      proc_tile3<true >(qH0,qH1,kc00,kc01,kc10,kc11,v0,v1,v2,v3,
                        oH0,oH1,oH2,oH3,mH,lH,qhi,s0,r,g,Plds[wave][0]);
    }
    if (ib < nbL){
      if (ib < nfL){
        proc_tile3<false>(qL0,qL1,kc00,kc01,kc10,kc11,v0,v1,v2,v3,
                          oL0,oL1,oL2,oL3,mL,lL,qlo,s0,r,g,Plds[wave][1]);
      } else {
        proc_tile3<true >(qL0,qL1,kc00,kc01,kc10,kc11,v0,v1,v2,v3,
                          oL0,oL1,oL2,oL3,mL,lL,qlo,s0,r,g,Plds[wave][1]);
      }
    }
    kc00=kn00; kc01=kn01; kc10=kn10; kc11=kn11;
  }

  // parity-1 wave publishes partial state for both tiles
  if (p == 1){
    float* bh_ = &Mbuf[pair][0][0][0];
    float* bl_ = &Mbuf[pair][1][0][0];
    #pragma unroll
    for (int i=0;i<4;i++){
      bh_[(0*4+i)*64 + lane] = oH0[i];
      bh_[(1*4+i)*64 + lane] = oH1[i];
      bh_[(2*4+i)*64 + lane] = oH2[i];
      bh_[(3*4+i)*64 + lane] = oH3[i];
      bh_[(16+i)*64 + lane] = mH[i];
      bh_[(20+i)*64 + lane] = lH[i];
      bl_[(0*4+i)*64 + lane] = oL0[i];
      bl_[(1*4+i)*64 + lane] = oL1[i];
      bl_[(2*4+i)*64 + lane] = oL2[i];
      bl_[(3*4+i)*64 + lane] = oL3[i];
      bl_[(16+i)*64 + lane] = mL[i];
      bl_[(20+i)*64 + lane] = lL[i];
    }
  }
  __syncthreads();
  if (p == 0){
#define MERGE(B, o0_, o1_, o2_, o3_, m_, l_) { \
    const float* b_ = B; \
    _Pragma("unroll") \
    for (int i=0;i<4;i++){ \
      const float m1 = b_[(16+i)*64 + lane]; \
      const float l1 = b_[(20+i)*64 + lane]; \
      const float mm = fmaxf(m_[i], m1); \
      const float c0 = exp2f(m_[i] - mm); \
      const float c1 = exp2f(m1 - mm); \
      l_[i] = l_[i]*c0 + l1*c1; \
      o0_[i] = o0_[i]*c0 + b_[(0*4+i)*64 + lane]*c1; \
      o1_[i] = o1_[i]*c0 + b_[(1*4+i)*64 + lane]*c1; \
      o2_[i] = o2_[i]*c0 + b_[(2*4+i)*64 + lane]*c1; \
      o3_[i] = o3_[i]*c0 + b_[(3*4+i)*64 + lane]*c1; \
    } }
    MERGE(&Mbuf[pair][0][0][0], oH0, oH1, oH2, oH3, mH, lH);
    MERGE(&Mbuf[pair][1][0][0], oL0, oL1, oL2, oL3, mL, lL);
#undef MERGE
    #pragma unroll
    for (int off=8; off>0; off>>=1){
      #pragma unroll
      for (int i=0;i<4;i++){
        lH[i] += __shfl_xor(lH[i], off);
        lL[i] += __shfl_xor(lL[i], off);
      }
    }
    float invL[4], invH[4];
    #pragma unroll
    for (int i=0;i<4;i++){ invH[i] = 1.0f/lH[i]; invL[i] = 1.0f/lL[i]; }
    #pragma unroll
    for (int i=0;i<4;i++){
      const size_t rowH = (size_t)(bq*TT + qhi + g*4 + i)*DM + h*HD;
      Ob[rowH + r]      = f2b(oH0[i]*invH[i]);
      Ob[rowH + 16 + r] = f2b(oH1[i]*invH[i]);
      Ob[rowH + 32 + r] = f2b(oH2[i]*invH[i]);
      Ob[rowH + 48 + r] = f2b(oH3[i]*invH[i]);
      const size_t rowL = (size_t)(bq*TT + qlo + g*4 + i)*DM + h*HD;
      Ob[rowL + r]      = f2b(oL0[i]*invL[i]);
      Ob[rowL + 16 + r] = f2b(oL1[i]*invL[i]);
      Ob[rowL + 32 + r] = f2b(oL2[i]*invL[i]);
      Ob[rowL + 48 + r] = f2b(oL3[i]*invL[i]);
    }
  }
}

extern "C" void kernel_launch(void* const* d_in, const int* in_sizes, int n_in,
                              void* d_out, int out_size, void* d_ws, size_t ws_size,
                              hipStream_t stream) {
  const float* X  = (const float*)d_in[0];
  const int* pos  = (const int*)d_in[1];
  const float* Wq = (const float*)d_in[2];
  const float* Wk = (const float*)d_in[3];
  const float* Wv = (const float*)d_in[4];
  const float* Wo = (const float*)d_in[5];
  float* out = (float*)d_out;

  char* ws = (char*)d_ws;
  u16* Xb = (u16*)ws;                                    // 8 MB (reused as Vt later)
  u16* Vt = (u16*)ws;                                    // aliases Xb (dead after QKV gemm)
  u16* Wb = (u16*)(ws + (size_t)8*1024*1024);            // 4 x 2 MB (q,k,v,o)
  u16* Qb = (u16*)(ws + (size_t)16*1024*1024);           // 8 MB
  u16* Kb = Qb + (size_t)BT*DM;                          // 8 MB
  u16* Vb = Kb + (size_t)BT*DM;                          // 8 MB
  u16* Ob = (u16*)(ws + (size_t)40*1024*1024);           // 8 MB

  const int DD = DM*DM;
  cvt_kernel<<<4096, 256, 0, stream>>>(X, Xb, BT*DM/4);
  cvt_w_kernel<<<4096, 256, 0, stream>>>(Wq, Wk, Wv, Wo, Wb);

  gemm128<0><<<dim3(24, 32), 256, 0, stream>>>(Xb, Wb, Qb, nullptr);
  rope_kernel<<<512, 256, 0, stream>>>(Qb, Kb, pos);
  transpose_v_kernel<<<1024, 256, 0, stream>>>(Vb, Vt);
  attn_kernel<<<1024, 256, 0, stream>>>(Qb, Kb, Vt, Ob);
  gemm128<1><<<dim3(8, 32), 256, 0, stream>>>(Ob, Wb + 3*DD, nullptr, out);
}

// Round 6
// 168.407 us; speedup vs baseline: 1.6216x; 1.1851x over previous
//
#include <hip/hip_runtime.h>
#include <hip/hip_bf16.h>

#define BB 2
#define TT 2048
#define DM 1024
#define NH 16
#define HD 64
#define BT (BB*TT)

typedef unsigned short u16;
typedef __attribute__((ext_vector_type(8))) short short8;
typedef __attribute__((ext_vector_type(4))) float f32x4;

__device__ __forceinline__ u16 f2b(float f){
  unsigned u = __builtin_bit_cast(unsigned, f);
  u += 0x7FFFu + ((u >> 16) & 1u);
  return (u16)(u >> 16);
}
__device__ __forceinline__ float b2f(u16 h){
  unsigned u = ((unsigned)h) << 16;
  return __builtin_bit_cast(float, u);
}

__device__ __forceinline__ void gll16(const u16* g, u16* l){
  __builtin_amdgcn_global_load_lds((const __attribute__((address_space(1))) void*)g,
                                   (__attribute__((address_space(3))) void*)l, 16, 0, 0);
}

// ---------------- f32 -> bf16 conversion (X) ----------------
__global__ __launch_bounds__(256) void cvt_kernel(const float* __restrict__ src,
                                                  u16* __restrict__ dst, int n4){
  int i = blockIdx.x*256 + threadIdx.x;
  if (i < n4){
    const float4 v = *(const float4*)(src + (size_t)i*4);
    ushort4 o;
    o.x = f2b(v.x); o.y = f2b(v.y); o.z = f2b(v.z); o.w = f2b(v.w);
    *(ushort4*)(dst + (size_t)i*4) = o;
  }
}

// ---------------- fused weight conversion (4 x 1M elems) ----------------
__global__ __launch_bounds__(256) void cvt_w_kernel(const float* __restrict__ w0,
                                                    const float* __restrict__ w1,
                                                    const float* __restrict__ w2,
                                                    const float* __restrict__ w3,
                                                    u16* __restrict__ dst){
  const int seg = blockIdx.x >> 10;
  const int i = (blockIdx.x & 1023)*256 + threadIdx.x;
  const float* src = (seg==0)?w0:(seg==1)?w1:(seg==2)?w2:w3;
  const float4 v = *(const float4*)(src + (size_t)i*4);
  ushort4 o;
  o.x = f2b(v.x); o.y = f2b(v.y); o.z = f2b(v.z); o.w = f2b(v.w);
  *(ushort4*)(dst + (size_t)seg*DM*DM + (size_t)i*4) = o;
}

// ---------------- 128x128-tile LDS-staged GEMM ----------------
#define FRAG(buf, row) (*(const short8*)((buf) + (size_t)(row)*32 + ((g ^ (((row)>>1)&3))*8)))

template<int MODE>
__global__ __launch_bounds__(256) void gemm128(const u16* __restrict__ A,
                                               const u16* __restrict__ W,
                                               u16* __restrict__ Ybf,
                                               float* __restrict__ Yf){
  __shared__ u16 sA0[4096], sB0[4096], sA1[4096], sB1[4096];
  const int tid = threadIdx.x;
  const int lane = tid & 63;
  const int wave = tid >> 6;
  const int r = lane & 15, g = lane >> 4;
  const int wr = wave >> 1, wc = wave & 1;
  const int m0 = blockIdx.y << 7;
  const int nn0 = blockIdx.x << 7;

  const int srow = tid >> 2;
  const int lcol = (((tid & 3) ^ ((srow >> 1) & 3))) * 8;

  const u16* gA0 = A + (size_t)(m0 + srow)*DM + lcol;
  const u16* gA1 = gA0 + (size_t)64*DM;
  const u16* gB0 = W + (size_t)(nn0 + srow)*DM + lcol;
  const u16* gB1 = gB0 + (size_t)64*DM;

  f32x4 acc[4][4];
  #pragma unroll
  for (int i=0;i<4;i++)
    #pragma unroll
    for (int j=0;j<4;j++) acc[i][j] = (f32x4){0.f,0.f,0.f,0.f};

#define STAGE(SA, SB, koff) { \
    gll16(gA0 + (koff), SA + (size_t)tid*8); \
    gll16(gA1 + (koff), SA + 2048 + (size_t)tid*8); \
    gll16(gB0 + (koff), SB + (size_t)tid*8); \
    gll16(gB1 + (koff), SB + 2048 + (size_t)tid*8); }

#define COMPUTE(SA, SB) { \
    short8 af[4], bf[4]; \
    _Pragma("unroll") \
    for (int f=0; f<4; f++){ \
      af[f] = FRAG(SA, wr*64 + f*16 + r); \
      bf[f] = FRAG(SB, wc*64 + f*16 + r); \
    } \
    _Pragma("unroll") \
    for (int fr=0; fr<4; fr++) \
      _Pragma("unroll") \
      for (int fn=0; fn<4; fn++) \
        acc[fr][fn] = __builtin_amdgcn_mfma_f32_16x16x32_bf16(af[fr], bf[fn], acc[fr][fn], 0,0,0); }

  STAGE(sA0, sB0, 0);
  __syncthreads();

  for (int t = 0; t < 32; t += 2){
    if (t + 1 < 32) STAGE(sA1, sB1, (t+1)*32);
    COMPUTE(sA0, sB0);
    __syncthreads();
    if (t + 2 < 32) STAGE(sA0, sB0, (t+2)*32);
    COMPUTE(sA1, sB1);
    __syncthreads();
  }

  #pragma unroll
  for (int fr=0; fr<4; fr++){
    #pragma unroll
    for (int i=0;i<4;i++){
      const int m = m0 + wr*64 + fr*16 + g*4 + i;
      #pragma unroll
      for (int fn=0; fn<4; fn++){
        const int nn = nn0 + wc*64 + fn*16 + r;
        if (MODE == 0){
          Ybf[(size_t)(nn >> 10)*BT*DM + (size_t)m*DM + (nn & 1023)] = f2b(acc[fr][fn][i]);
        } else {
          Yf[(size_t)m*DM + nn] = acc[fr][fn][i];
        }
      }
    }
  }
#undef STAGE
#undef COMPUTE
}

// ---------------- RoPE on Q,K ----------------
__global__ __launch_bounds__(256) void rope_kernel(u16* __restrict__ Qb, u16* __restrict__ Kb,
                                                   const int* __restrict__ pos){
  const int t = blockIdx.x*256 + threadIdx.x;
  const int m = t >> 5;
  const int fi = t & 31;
  const float invf = __expf(-(float)fi * 0.28782313662425575f);
  float s, c;
  sincosf((float)pos[m] * invf, &s, &c);
  const size_t base = (size_t)m*DM + fi*2;
  #pragma unroll
  for (int h=0; h<NH; h++){
    const size_t a = base + h*HD;
    {
      const float x0 = b2f(Qb[a]), x1 = b2f(Qb[a+1]);
      Qb[a]   = f2b(c*x0 - s*x1);
      Qb[a+1] = f2b(c*x1 + s*x0);
    }
    {
      const float x0 = b2f(Kb[a]), x1 = b2f(Kb[a+1]);
      Kb[a]   = f2b(c*x0 - s*x1);
      Kb[a+1] = f2b(c*x1 + s*x0);
    }
  }
}

// ---------------- V transpose ----------------
__global__ __launch_bounds__(256) void transpose_v_kernel(const u16* __restrict__ Vb,
                                                          u16* __restrict__ Vt){
  __shared__ u16 tile[64][72];
  const int bh = blockIdx.x >> 5;
  const int sc = blockIdx.x & 31;
  const int bq = bh >> 4, h = bh & 15;
  const int s0 = sc*64;
  {
    const int row = threadIdx.x >> 3;
    const int c8 = (threadIdx.x & 7)*8;
    #pragma unroll
    for (int rr = 0; rr < 64; rr += 32){
      const short8 v = *(const short8*)(Vb + (size_t)(bq*TT + s0 + row + rr)*DM + h*HD + c8);
      *(short8*)(&tile[row+rr][c8]) = v;
    }
  }
  __syncthreads();
  {
    const int d = threadIdx.x >> 3;
    const int s8 = (threadIdx.x & 7)*8;
    #pragma unroll
    for (int dd = 0; dd < 64; dd += 32){
      short8 ov;
      #pragma unroll
      for (int j=0;j<8;j++) ov[j] = (short)tile[s8+j][d+dd];
      *(short8*)(Vt + ((size_t)bh*HD + d + dd)*TT + s0 + s8) = ov;
    }
  }
}

// ---------- causal flash attention: 128-row panels, LDS-staged KV ----------
// log2-domain: scores scaled by 0.125/ln2; exp2f everywhere. defer-max (T13).
#define SC2 0.18033688011112042f
#define THR2 11.541560327111707f

template<bool MASKED>
__device__ __forceinline__ void proc_tileS(
    const short8 qf0, const short8 qf1,
    const short8 k00, const short8 k01, const short8 k10, const short8 k11,
    const short8 v0, const short8 v1, const short8 v2, const short8 v3,
    f32x4& o0, f32x4& o1, f32x4& o2, f32x4& o3,
    float (&mrow)[4], float (&lsum)[4],
    const int q0, const int s0, const int r, const int g,
    u16 (*pbuf)[40])
{
  f32x4 sa0={0,0,0,0}, sa1={0,0,0,0};
  sa0 = __builtin_amdgcn_mfma_f32_16x16x32_bf16(qf0, k00, sa0, 0,0,0);
  sa0 = __builtin_amdgcn_mfma_f32_16x16x32_bf16(qf1, k01, sa0, 0,0,0);
  sa1 = __builtin_amdgcn_mfma_f32_16x16x32_bf16(qf0, k10, sa1, 0,0,0);
  sa1 = __builtin_amdgcn_mfma_f32_16x16x32_bf16(qf1, k11, sa1, 0,0,0);

  float sv0[4], sv1[4], lm[4];
  bool ok = true;
  #pragma unroll
  for (int i=0;i<4;i++){
    if (MASKED){
      const int q = q0 + g*4 + i;
      sv0[i] = (s0 + r      <= q) ? sa0[i]*SC2 : -3.0e38f;
      sv1[i] = (s0 + 16 + r <= q) ? sa1[i]*SC2 : -3.0e38f;
    } else {
      sv0[i] = sa0[i]*SC2;
      sv1[i] = sa1[i]*SC2;
    }
    lm[i] = fmaxf(sv0[i], sv1[i]);
    ok = ok && (lm[i] <= mrow[i] + THR2);
  }
  if (!__all((int)ok)){
    float pm[4];
    #pragma unroll
    for (int i=0;i<4;i++) pm[i] = lm[i];
    #pragma unroll
    for (int off=8; off>0; off>>=1){
      #pragma unroll
      for (int i=0;i<4;i++) pm[i] = fmaxf(pm[i], __shfl_xor(pm[i], off));
    }
    #pragma unroll
    for (int i=0;i<4;i++){
      const float mn = fmaxf(mrow[i], pm[i]);
      const float corr = exp2f(mrow[i] - mn);
      mrow[i] = mn;
      lsum[i] *= corr;
      o0[i] *= corr; o1[i] *= corr; o2[i] *= corr; o3[i] *= corr;
    }
  }
  #pragma unroll
  for (int i=0;i<4;i++){
    const float p0 = exp2f(sv0[i] - mrow[i]);
    const float p1 = exp2f(sv1[i] - mrow[i]);
    lsum[i] += p0 + p1;
    pbuf[g*4+i][r]      = f2b(p0);
    pbuf[g*4+i][16 + r] = f2b(p1);
  }
  const short8 pf = *(const short8*)(&pbuf[r][g*8]);
  o0 = __builtin_amdgcn_mfma_f32_16x16x32_bf16(pf, v0, o0, 0,0,0);
  o1 = __builtin_amdgcn_mfma_f32_16x16x32_bf16(pf, v1, o1, 0,0,0);
  o2 = __builtin_amdgcn_mfma_f32_16x16x32_bf16(pf, v2, o2, 0,0,0);
  o3 = __builtin_amdgcn_mfma_f32_16x16x32_bf16(pf, v3, o3, 0,0,0);
}

__global__ __launch_bounds__(256) void attn_kernel(const u16* __restrict__ Qb,
                                                   const u16* __restrict__ Kb,
                                                   const u16* __restrict__ Vt,
                                                   u16* __restrict__ Ob){
  __shared__ u16 Ks[2][2048];        // 32 rows x 64 d, granule-swizzled g^(row&7)
  __shared__ u16 Vs[2][2048];        // 64 d x 32 s, granule-swizzled g^((d>>1)&3)
  __shared__ u16 Plds[4][16][40];    // per-wave P tile (shared by both q-tiles)
  const int tid = threadIdx.x;
  const int lane = tid & 63;
  const int wave = tid >> 6;
  const int r = lane & 15, g = lane >> 4;

  const int bx = blockIdx.x;             // 0..15
  const int by = blockIdx.y;             // 0..31  (= bh)
  const int bh = by;
  const int qp = (by & 16) ? bx : (15 - bx);   // panel; complement pairing for balance
  const int bq = bh >> 4;
  const int h  = bh & 15;
  const int w0 = qp*128 + wave*32;       // this wave's first q row (within T)

  const int nb  = (qp + 1)*4;            // KV blocks staged by the workgroup
  const int nbw = qp*4 + wave + 1;       // KV blocks computed by this wave

  // ---- Q fragments (2 tiles of 16 rows) ----
  const u16* Qrow0 = Qb + (size_t)(bq*TT + w0 + r)*DM + h*HD;
  const u16* Qrow1 = Qrow0 + (size_t)16*DM;
  const short8 qA0 = *(const short8*)(Qrow0 + g*8);
  const short8 qA1 = *(const short8*)(Qrow0 + 32 + g*8);
  const short8 qB0 = *(const short8*)(Qrow1 + g*8);
  const short8 qB1 = *(const short8*)(Qrow1 + 32 + g*8);

  // ---- staging source maps (pre-swizzled global columns) ----
  const int krow = tid >> 3, kq = tid & 7;
  const int vd   = tid >> 2, vq = tid & 3;
  const u16* Ksrc = Kb + (size_t)(bq*TT + krow)*DM + h*HD + ((kq ^ (krow & 7))*8);
  const u16* Vsrc = Vt + (size_t)bh*HD*TT + (size_t)vd*TT + ((vq ^ ((vd >> 1) & 3))*8);

  f32x4 oA0={0,0,0,0}, oA1={0,0,0,0}, oA2={0,0,0,0}, oA3={0,0,0,0};
  f32x4 oB0={0,0,0,0}, oB1={0,0,0,0}, oB2={0,0,0,0}, oB3={0,0,0,0};
  float mA[4], lA[4], mB[4], lB[4];
  #pragma unroll
  for (int i=0;i<4;i++){ mA[i]=0.f; lA[i]=0.f; mB[i]=0.f; lB[i]=0.f; }

#define STAGEKV(buf, s0) { \
    gll16(Ksrc + (size_t)(s0)*DM, Ks[buf] + (size_t)tid*8); \
    gll16(Vsrc + (s0),            Vs[buf] + (size_t)tid*8); }

  STAGEKV(0, 0);
  __syncthreads();

  for (int ib = 0; ib < nb; ib++){
    const int cur = ib & 1;
    if (ib + 1 < nb) STAGEKV(cur ^ 1, (ib + 1)*32);
    if (ib < nbw){
      const int s0 = ib << 5;
      const u16* kb_ = Ks[cur];
      const u16* vb_ = Vs[cur];
      const int sw = (g ^ (r & 7))*8;
      const int sw4 = ((g + 4) ^ (r & 7))*8;
      const short8 k00 = *(const short8*)(kb_ + r*64 + sw);
      const short8 k01 = *(const short8*)(kb_ + r*64 + sw4);
      const short8 k10 = *(const short8*)(kb_ + (16 + r)*64 + sw);
      const short8 k11 = *(const short8*)(kb_ + (16 + r)*64 + sw4);
      const int vsw = (g ^ ((r >> 1) & 3))*8;
      const short8 v0 = *(const short8*)(vb_ + (r      )*32 + vsw);
      const short8 v1 = *(const short8*)(vb_ + (16 + r)*32 + vsw);
      const short8 v2 = *(const short8*)(vb_ + (32 + r)*32 + vsw);
      const short8 v3 = *(const short8*)(vb_ + (48 + r)*32 + vsw);
      if (ib < nbw - 1){
        proc_tileS<false>(qA0,qA1,k00,k01,k10,k11,v0,v1,v2,v3,
                          oA0,oA1,oA2,oA3,mA,lA,w0,s0,r,g,Plds[wave]);
        proc_tileS<false>(qB0,qB1,k00,k01,k10,k11,v0,v1,v2,v3,
                          oB0,oB1,oB2,oB3,mB,lB,w0+16,s0,r,g,Plds[wave]);
      } else {
        proc_tileS<true >(qA0,qA1,k00,k01,k10,k11,v0,v1,v2,v3,
                          oA0,oA1,oA2,oA3,mA,lA,w0,s0,r,g,Plds[wave]);
        proc_tileS<true >(qB0,qB1,k00,k01,k10,k11,v0,v1,v2,v3,
                          oB0,oB1,oB2,oB3,mB,lB,w0+16,s0,r,g,Plds[wave]);
      }
    }
    __syncthreads();
  }
#undef STAGEKV

  // ---- final row-sum reduction + output ----
  #pragma unroll
  for (int off=8; off>0; off>>=1){
    #pragma unroll
    for (int i=0;i<4;i++){
      lA[i] += __shfl_xor(lA[i], off);
      lB[i] += __shfl_xor(lB[i], off);
    }
  }
  float invA[4], invB[4];
  #pragma unroll
  for (int i=0;i<4;i++){ invA[i] = 1.0f/lA[i]; invB[i] = 1.0f/lB[i]; }
  #pragma unroll
  for (int i=0;i<4;i++){
    const size_t rowA = (size_t)(bq*TT + w0 + g*4 + i)*DM + h*HD;
    Ob[rowA + r]      = f2b(oA0[i]*invA[i]);
    Ob[rowA + 16 + r] = f2b(oA1[i]*invA[i]);
    Ob[rowA + 32 + r] = f2b(oA2[i]*invA[i]);
    Ob[rowA + 48 + r] = f2b(oA3[i]*invA[i]);
    const size_t rowB = rowA + (size_t)16*DM;
    Ob[rowB + r]      = f2b(oB0[i]*invB[i]);
    Ob[rowB + 16 + r] = f2b(oB1[i]*invB[i]);
    Ob[rowB + 32 + r] = f2b(oB2[i]*invB[i]);
    Ob[rowB + 48 + r] = f2b(oB3[i]*invB[i]);
  }
}

extern "C" void kernel_launch(void* const* d_in, const int* in_sizes, int n_in,
                              void* d_out, int out_size, void* d_ws, size_t ws_size,
                              hipStream_t stream) {
  const float* X  = (const float*)d_in[0];
  const int* pos  = (const int*)d_in[1];
  const float* Wq = (const float*)d_in[2];
  const float* Wk = (const float*)d_in[3];
  const float* Wv = (const float*)d_in[4];
  const float* Wo = (const float*)d_in[5];
  float* out = (float*)d_out;

  char* ws = (char*)d_ws;
  u16* Xb = (u16*)ws;                                    // 8 MB (reused as Vt later)
  u16* Vt = (u16*)ws;                                    // aliases Xb (dead after QKV gemm)
  u16* Wb = (u16*)(ws + (size_t)8*1024*1024);            // 4 x 2 MB (q,k,v,o)
  u16* Qb = (u16*)(ws + (size_t)16*1024*1024);           // 8 MB
  u16* Kb = Qb + (size_t)BT*DM;                          // 8 MB
  u16* Vb = Kb + (size_t)BT*DM;                          // 8 MB
  u16* Ob = (u16*)(ws + (size_t)40*1024*1024);           // 8 MB

  const int DD = DM*DM;
  cvt_kernel<<<4096, 256, 0, stream>>>(X, Xb, BT*DM/4);
  cvt_w_kernel<<<4096, 256, 0, stream>>>(Wq, Wk, Wv, Wo, Wb);

  gemm128<0><<<dim3(24, 32), 256, 0, stream>>>(Xb, Wb, Qb, nullptr);
  rope_kernel<<<512, 256, 0, stream>>>(Qb, Kb, pos);
  transpose_v_kernel<<<1024, 256, 0, stream>>>(Vb, Vt);
  attn_kernel<<<dim3(16, 32), 256, 0, stream>>>(Qb, Kb, Vt, Ob);
  gemm128<1><<<dim3(8, 32), 256, 0, stream>>>(Ob, Wb + 3*DD, nullptr, out);
}

// Round 7
// 131.205 us; speedup vs baseline: 2.0814x; 1.2835x over previous
//
#include <hip/hip_runtime.h>
#include <hip/hip_bf16.h>

#define BB 2
#define TT 2048
#define DM 1024
#define NH 16
#define HD 64
#define BT (BB*TT)
#define SC2 0.18033688011112042f   // 0.125 / ln(2)

typedef unsigned short u16;
typedef __attribute__((ext_vector_type(8))) short short8;
typedef __attribute__((ext_vector_type(4))) float f32x4;

__device__ __forceinline__ u16 f2b(float f){
  unsigned u = __builtin_bit_cast(unsigned, f);
  u += 0x7FFFu + ((u >> 16) & 1u);
  return (u16)(u >> 16);
}
__device__ __forceinline__ float b2f(u16 h){
  unsigned u = ((unsigned)h) << 16;
  return __builtin_bit_cast(float, u);
}

__device__ __forceinline__ void gll16(const u16* g, u16* l){
  __builtin_amdgcn_global_load_lds((const __attribute__((address_space(1))) void*)g,
                                   (__attribute__((address_space(3))) void*)l, 16, 0, 0);
}

// ---------------- f32 -> bf16 conversion (X) ----------------
__global__ __launch_bounds__(256) void cvt_kernel(const float* __restrict__ src,
                                                  u16* __restrict__ dst, int n4){
  int i = blockIdx.x*256 + threadIdx.x;
  if (i < n4){
    const float4 v = *(const float4*)(src + (size_t)i*4);
    ushort4 o;
    o.x = f2b(v.x); o.y = f2b(v.y); o.z = f2b(v.z); o.w = f2b(v.w);
    *(ushort4*)(dst + (size_t)i*4) = o;
  }
}

// ---------------- fused weight conversion (4 x 1M elems) ----------------
__global__ __launch_bounds__(256) void cvt_w_kernel(const float* __restrict__ w0,
                                                    const float* __restrict__ w1,
                                                    const float* __restrict__ w2,
                                                    const float* __restrict__ w3,
                                                    u16* __restrict__ dst){
  const int seg = blockIdx.x >> 10;
  const int i = (blockIdx.x & 1023)*256 + threadIdx.x;
  const float* src = (seg==0)?w0:(seg==1)?w1:(seg==2)?w2:w3;
  const float4 v = *(const float4*)(src + (size_t)i*4);
  ushort4 o;
  o.x = f2b(v.x); o.y = f2b(v.y); o.z = f2b(v.z); o.w = f2b(v.w);
  *(ushort4*)(dst + (size_t)seg*DM*DM + (size_t)i*4) = o;
}

// ---------------- 128x128-tile LDS-staged GEMM ----------------
#define FRAG(buf, row) (*(const short8*)((buf) + (size_t)(row)*32 + ((g ^ (((row)>>1)&3))*8)))

template<int MODE>
__global__ __launch_bounds__(256) void gemm128(const u16* __restrict__ A,
                                               const u16* __restrict__ W,
                                               u16* __restrict__ Ybf,
                                               float* __restrict__ Yf){
  __shared__ u16 sA0[4096], sB0[4096], sA1[4096], sB1[4096];
  const int tid = threadIdx.x;
  const int lane = tid & 63;
  const int wave = tid >> 6;
  const int r = lane & 15, g = lane >> 4;
  const int wr = wave >> 1, wc = wave & 1;
  const int m0 = blockIdx.y << 7;
  const int nn0 = blockIdx.x << 7;

  const int srow = tid >> 2;
  const int lcol = (((tid & 3) ^ ((srow >> 1) & 3))) * 8;

  const u16* gA0 = A + (size_t)(m0 + srow)*DM + lcol;
  const u16* gA1 = gA0 + (size_t)64*DM;
  const u16* gB0 = W + (size_t)(nn0 + srow)*DM + lcol;
  const u16* gB1 = gB0 + (size_t)64*DM;

  f32x4 acc[4][4];
  #pragma unroll
  for (int i=0;i<4;i++)
    #pragma unroll
    for (int j=0;j<4;j++) acc[i][j] = (f32x4){0.f,0.f,0.f,0.f};

#define STAGE(SA, SB, koff) { \
    gll16(gA0 + (koff), SA + (size_t)tid*8); \
    gll16(gA1 + (koff), SA + 2048 + (size_t)tid*8); \
    gll16(gB0 + (koff), SB + (size_t)tid*8); \
    gll16(gB1 + (koff), SB + 2048 + (size_t)tid*8); }

#define COMPUTE(SA, SB) { \
    short8 af[4], bf[4]; \
    _Pragma("unroll") \
    for (int f=0; f<4; f++){ \
      af[f] = FRAG(SA, wr*64 + f*16 + r); \
      bf[f] = FRAG(SB, wc*64 + f*16 + r); \
    } \
    _Pragma("unroll") \
    for (int fr=0; fr<4; fr++) \
      _Pragma("unroll") \
      for (int fn=0; fn<4; fn++) \
        acc[fr][fn] = __builtin_amdgcn_mfma_f32_16x16x32_bf16(af[fr], bf[fn], acc[fr][fn], 0,0,0); }

  STAGE(sA0, sB0, 0);
  __syncthreads();

  for (int t = 0; t < 32; t += 2){
    if (t + 1 < 32) STAGE(sA1, sB1, (t+1)*32);
    COMPUTE(sA0, sB0);
    __syncthreads();
    if (t + 2 < 32) STAGE(sA0, sB0, (t+2)*32);
    COMPUTE(sA1, sB1);
    __syncthreads();
  }

  #pragma unroll
  for (int fr=0; fr<4; fr++){
    #pragma unroll
    for (int i=0;i<4;i++){
      const int m = m0 + wr*64 + fr*16 + g*4 + i;
      #pragma unroll
      for (int fn=0; fn<4; fn++){
        const int nn = nn0 + wc*64 + fn*16 + r;
        if (MODE == 0){
          Ybf[(size_t)(nn >> 10)*BT*DM + (size_t)m*DM + (nn & 1023)] = f2b(acc[fr][fn][i]);
        } else {
          Yf[(size_t)m*DM + nn] = acc[fr][fn][i];
        }
      }
    }
  }
#undef STAGE
#undef COMPUTE
}

// ---------------- RoPE on Q,K (Q pre-scaled by SC2) ----------------
__global__ __launch_bounds__(256) void rope_kernel(u16* __restrict__ Qb, u16* __restrict__ Kb,
                                                   const int* __restrict__ pos){
  const int t = blockIdx.x*256 + threadIdx.x;
  const int m = t >> 5;
  const int fi = t & 31;
  const float invf = __expf(-(float)fi * 0.28782313662425575f);
  float s, c;
  sincosf((float)pos[m] * invf, &s, &c);
  const float cq = c*SC2, sq = s*SC2;
  const size_t base = (size_t)m*DM + fi*2;
  #pragma unroll
  for (int h=0; h<NH; h++){
    const size_t a = base + h*HD;
    {
      const float x0 = b2f(Qb[a]), x1 = b2f(Qb[a+1]);
      Qb[a]   = f2b(cq*x0 - sq*x1);
      Qb[a+1] = f2b(cq*x1 + sq*x0);
    }
    {
      const float x0 = b2f(Kb[a]), x1 = b2f(Kb[a+1]);
      Kb[a]   = f2b(c*x0 - s*x1);
      Kb[a+1] = f2b(c*x1 + s*x0);
    }
  }
}

// -------- V transpose, key-INTERLEAVED within 32-groups --------
// storage col s' holds logical s = 32*(s'>>5) + ((s'&31)>>1) + (s'&1)*16
__global__ __launch_bounds__(256) void transpose_v_kernel(const u16* __restrict__ Vb,
                                                          u16* __restrict__ Vt){
  __shared__ u16 tile[64][72];
  const int bh = blockIdx.x >> 5;
  const int sc = blockIdx.x & 31;
  const int bq = bh >> 4, h = bh & 15;
  const int s0 = sc*64;
  {
    const int row = threadIdx.x >> 3;
    const int c8 = (threadIdx.x & 7)*8;
    #pragma unroll
    for (int rr = 0; rr < 64; rr += 32){
      const short8 v = *(const short8*)(Vb + (size_t)(bq*TT + s0 + row + rr)*DM + h*HD + c8);
      *(short8*)(&tile[row+rr][c8]) = v;
    }
  }
  __syncthreads();
  {
    const int d = threadIdx.x >> 3;
    const int s8 = (threadIdx.x & 7)*8;
    #pragma unroll
    for (int dd = 0; dd < 64; dd += 32){
      short8 ov;
      #pragma unroll
      for (int j=0;j<8;j++){
        const int sl = s8 + j;
        const int w = sl & 31;
        const int slog = (sl & 32) + (w >> 1) + ((w & 1) << 4);
        ov[j] = (short)tile[slog][d+dd];
      }
      *(short8*)(Vt + ((size_t)bh*HD + d + dd)*TT + s0 + s8) = ov;
    }
  }
}

// ---------- causal flash attention: paired 64-row panels, LDS KV, m=0 softmax ----------
template<bool MASKED>
__device__ __forceinline__ void proc_fast(
    const short8 qf0, const short8 qf1,
    const short8 k00, const short8 k01, const short8 k10, const short8 k11,
    const short8 v0, const short8 v1, const short8 v2, const short8 v3,
    f32x4& o0, f32x4& o1, f32x4& o2, f32x4& o3,
    float (&lsum)[4],
    const int q0, const int s0, const int r, const int g,
    u16 (*pbuf)[40])
{
  f32x4 sa0={0,0,0,0}, sa1={0,0,0,0};
  __builtin_amdgcn_s_setprio(1);
  sa0 = __builtin_amdgcn_mfma_f32_16x16x32_bf16(qf0, k00, sa0, 0,0,0);
  sa0 = __builtin_amdgcn_mfma_f32_16x16x32_bf16(qf1, k01, sa0, 0,0,0);
  sa1 = __builtin_amdgcn_mfma_f32_16x16x32_bf16(qf0, k10, sa1, 0,0,0);
  sa1 = __builtin_amdgcn_mfma_f32_16x16x32_bf16(qf1, k11, sa1, 0,0,0);
  __builtin_amdgcn_s_setprio(0);
  #pragma unroll
  for (int i=0;i<4;i++){
    float a = sa0[i], b = sa1[i];
    if (MASKED){
      const int q = q0 + g*4 + i;
      a = (s0 + r      <= q) ? a : -3.0e38f;
      b = (s0 + 16 + r <= q) ? b : -3.0e38f;
    }
    const float p0 = exp2f(a);
    const float p1 = exp2f(b);
    lsum[i] += p0 + p1;
    unsigned w;
    asm("v_cvt_pk_bf16_f32 %0, %1, %2" : "=v"(w) : "v"(p0), "v"(p1));
    *(unsigned*)(&pbuf[g*4+i][r*2]) = w;   // keys r (lo half), 16+r (hi half) interleaved
  }
  const short8 pf = *(const short8*)(&pbuf[r][g*8]);
  __builtin_amdgcn_s_setprio(1);
  o0 = __builtin_amdgcn_mfma_f32_16x16x32_bf16(pf, v0, o0, 0,0,0);
  o1 = __builtin_amdgcn_mfma_f32_16x16x32_bf16(pf, v1, o1, 0,0,0);
  o2 = __builtin_amdgcn_mfma_f32_16x16x32_bf16(pf, v2, o2, 0,0,0);
  o3 = __builtin_amdgcn_mfma_f32_16x16x32_bf16(pf, v3, o3, 0,0,0);
  __builtin_amdgcn_s_setprio(0);
}

__global__ __launch_bounds__(256) void attn_kernel(const u16* __restrict__ Qb,
                                                   const u16* __restrict__ Kb,
                                                   const u16* __restrict__ Vt,
                                                   u16* __restrict__ Ob){
  __shared__ u16 Ks[2][4096];        // 64 rows x 64 d, granule-swizzled phys = log ^ (row&7)
  __shared__ u16 Vs[2][4096];        // 64 d x 64 s' (interleaved), same swizzle on d
  __shared__ u16 Plds[4][16][40];
  const int tid = threadIdx.x;
  const int lane = tid & 63;
  const int wave = tid >> 6;
  const int r = lane & 15, g = lane >> 4;

  const int pp = blockIdx.x;             // 0..15 (panel pair)
  const int bh = blockIdx.y;             // 0..31
  const int bq = bh >> 4, h = bh & 15;
  const int lo = pp, hi = 31 - pp;
  const int w0A = lo*64 + wave*16;
  const int w0B = hi*64 + wave*16;
  const int sAd = (w0A >> 5) << 5;       // diagonal 32-block start for tile A
  const int sBd = (w0B >> 5) << 5;
  const int nb = hi + 1;                 // 64-row KV stage iterations

  // ---- Q fragments (pre-scaled by SC2 in rope) ----
  const u16* QrowA = Qb + (size_t)(bq*TT + w0A + r)*DM + h*HD;
  const u16* QrowB = Qb + (size_t)(bq*TT + w0B + r)*DM + h*HD;
  const short8 qA0 = *(const short8*)(QrowA + g*8);
  const short8 qA1 = *(const short8*)(QrowA + 32 + g*8);
  const short8 qB0 = *(const short8*)(QrowB + g*8);
  const short8 qB1 = *(const short8*)(QrowB + 32 + g*8);

  // ---- staging sources (pre-swizzled) ----
  const int srow = tid >> 3;
  const int scol = ((tid & 7) ^ (srow & 7)) * 8;
  const u16* Ksrc = Kb + (size_t)(bq*TT + srow)*DM + h*HD + scol;
  const u16* Vsrc = Vt + (size_t)bh*HD*TT + (size_t)srow*TT + scol;

  f32x4 oA0={0,0,0,0}, oA1={0,0,0,0}, oA2={0,0,0,0}, oA3={0,0,0,0};
  f32x4 oB0={0,0,0,0}, oB1={0,0,0,0}, oB2={0,0,0,0}, oB3={0,0,0,0};
  float lA[4] = {0.f,0.f,0.f,0.f}, lB[4] = {0.f,0.f,0.f,0.f};

#define STAGEKV(B, S64) { \
    gll16(Ksrc + (size_t)(S64)*DM,        Ks[B] + (size_t)tid*8); \
    gll16(Ksrc + (size_t)((S64)+32)*DM,   Ks[B] + 2048 + (size_t)tid*8); \
    gll16(Vsrc + (S64),                   Vs[B] + (size_t)tid*8); \
    gll16(Vsrc + (size_t)32*TT + (S64),   Vs[B] + 2048 + (size_t)tid*8); }

  STAGEKV(0, 0);
  __syncthreads();

  for (int ib = 0; ib < nb; ib++){
    const int cur = ib & 1;
    if (ib + 1 < nb) STAGEKV(cur ^ 1, (ib + 1)*64);
    const u16* kb_ = Ks[cur];
    const u16* vb_ = Vs[cur];
    #pragma unroll
    for (int half = 0; half < 2; half++){
      const int s0 = ib*64 + half*32;
      if (s0 > sBd) continue;            // wave-uniform
      const int rb = half*32 + r;
      const int ph0 = (g ^ (r & 7))*8;
      const int ph1 = ((g + 4) ^ (r & 7))*8;
      const short8 k00 = *(const short8*)(kb_ + (size_t)rb*64 + ph0);
      const short8 k01 = *(const short8*)(kb_ + (size_t)rb*64 + ph1);
      const short8 k10 = *(const short8*)(kb_ + (size_t)(rb+16)*64 + ph0);
      const short8 k11 = *(const short8*)(kb_ + (size_t)(rb+16)*64 + ph1);
      const int vc = ((half*4 + g) ^ (r & 7))*8;
      const short8 v0 = *(const short8*)(vb_ + (size_t)(r     )*64 + vc);
      const short8 v1 = *(const short8*)(vb_ + (size_t)(16 + r)*64 + vc);
      const short8 v2 = *(const short8*)(vb_ + (size_t)(32 + r)*64 + vc);
      const short8 v3 = *(const short8*)(vb_ + (size_t)(48 + r)*64 + vc);
      if (s0 <= sAd){
        if (s0 == sAd) proc_fast<true >(qA0,qA1,k00,k01,k10,k11,v0,v1,v2,v3,
                                        oA0,oA1,oA2,oA3,lA,w0A,s0,r,g,Plds[wave]);
        else           proc_fast<false>(qA0,qA1,k00,k01,k10,k11,v0,v1,v2,v3,
                                        oA0,oA1,oA2,oA3,lA,w0A,s0,r,g,Plds[wave]);
      }
      if (s0 == sBd) proc_fast<true >(qB0,qB1,k00,k01,k10,k11,v0,v1,v2,v3,
                                      oB0,oB1,oB2,oB3,lB,w0B,s0,r,g,Plds[wave]);
      else           proc_fast<false>(qB0,qB1,k00,k01,k10,k11,v0,v1,v2,v3,
                                      oB0,oB1,oB2,oB3,lB,w0B,s0,r,g,Plds[wave]);
    }
    __syncthreads();
  }
#undef STAGEKV

  // ---- final row-sum reduction (across the 16 key-lanes) + output ----
  #pragma unroll
  for (int off=8; off>0; off>>=1){
    #pragma unroll
    for (int i=0;i<4;i++){
      lA[i] += __shfl_xor(lA[i], off);
      lB[i] += __shfl_xor(lB[i], off);
    }
  }
  float invA[4], invB[4];
  #pragma unroll
  for (int i=0;i<4;i++){ invA[i] = 1.0f/lA[i]; invB[i] = 1.0f/lB[i]; }
  #pragma unroll
  for (int i=0;i<4;i++){
    const size_t rowA = (size_t)(bq*TT + w0A + g*4 + i)*DM + h*HD;
    Ob[rowA + r]      = f2b(oA0[i]*invA[i]);
    Ob[rowA + 16 + r] = f2b(oA1[i]*invA[i]);
    Ob[rowA + 32 + r] = f2b(oA2[i]*invA[i]);
    Ob[rowA + 48 + r] = f2b(oA3[i]*invA[i]);
    const size_t rowB = (size_t)(bq*TT + w0B + g*4 + i)*DM + h*HD;
    Ob[rowB + r]      = f2b(oB0[i]*invB[i]);
    Ob[rowB + 16 + r] = f2b(oB1[i]*invB[i]);
    Ob[rowB + 32 + r] = f2b(oB2[i]*invB[i]);
    Ob[rowB + 48 + r] = f2b(oB3[i]*invB[i]);
  }
}

extern "C" void kernel_launch(void* const* d_in, const int* in_sizes, int n_in,
                              void* d_out, int out_size, void* d_ws, size_t ws_size,
                              hipStream_t stream) {
  const float* X  = (const float*)d_in[0];
  const int* pos  = (const int*)d_in[1];
  const float* Wq = (const float*)d_in[2];
  const float* Wk = (const float*)d_in[3];
  const float* Wv = (const float*)d_in[4];
  const float* Wo = (const float*)d_in[5];
  float* out = (float*)d_out;

  char* ws = (char*)d_ws;
  u16* Xb = (u16*)ws;                                    // 8 MB (reused as Vt later)
  u16* Vt = (u16*)ws;                                    // aliases Xb (dead after QKV gemm)
  u16* Wb = (u16*)(ws + (size_t)8*1024*1024);            // 4 x 2 MB (q,k,v,o)
  u16* Qb = (u16*)(ws + (size_t)16*1024*1024);           // 8 MB
  u16* Kb = Qb + (size_t)BT*DM;                          // 8 MB
  u16* Vb = Kb + (size_t)BT*DM;                          // 8 MB
  u16* Ob = (u16*)(ws + (size_t)40*1024*1024);           // 8 MB

  const int DD = DM*DM;
  cvt_kernel<<<4096, 256, 0, stream>>>(X, Xb, BT*DM/4);
  cvt_w_kernel<<<4096, 256, 0, stream>>>(Wq, Wk, Wv, Wo, Wb);

  gemm128<0><<<dim3(24, 32), 256, 0, stream>>>(Xb, Wb, Qb, nullptr);
  rope_kernel<<<512, 256, 0, stream>>>(Qb, Kb, pos);
  transpose_v_kernel<<<1024, 256, 0, stream>>>(Vb, Vt);
  attn_kernel<<<dim3(16, 32), 256, 0, stream>>>(Qb, Kb, Vt, Ob);
  gemm128<1><<<dim3(8, 32), 256, 0, stream>>>(Ob, Wb + 3*DD, nullptr, out);
}

// Round 8
// 123.667 us; speedup vs baseline: 2.2083x; 1.0610x over previous
//
#include <hip/hip_runtime.h>
#include <hip/hip_bf16.h>

#define BB 2
#define TT 2048
#define DM 1024
#define NH 16
#define HD 64
#define BT (BB*TT)
#define SC2 0.18033688011112042f   // 0.125 / ln(2)

typedef unsigned short u16;
typedef __attribute__((ext_vector_type(8))) short short8;
typedef __attribute__((ext_vector_type(4))) float f32x4;

__device__ __forceinline__ u16 f2b(float f){
  unsigned u = __builtin_bit_cast(unsigned, f);
  u += 0x7FFFu + ((u >> 16) & 1u);
  return (u16)(u >> 16);
}
__device__ __forceinline__ float b2f(u16 h){
  unsigned u = ((unsigned)h) << 16;
  return __builtin_bit_cast(float, u);
}

__device__ __forceinline__ void gll16(const u16* g, u16* l){
  __builtin_amdgcn_global_load_lds((const __attribute__((address_space(1))) void*)g,
                                   (__attribute__((address_space(3))) void*)l, 16, 0, 0);
}

// ---------------- fused f32 -> bf16 conversion (X + 4 weights) ----------------
__global__ __launch_bounds__(256) void cvt_all_kernel(const float* __restrict__ X,
                                                      const float* __restrict__ w0,
                                                      const float* __restrict__ w1,
                                                      const float* __restrict__ w2,
                                                      const float* __restrict__ w3,
                                                      u16* __restrict__ Xb,
                                                      u16* __restrict__ Wb){
  const int b = blockIdx.x;
  const float* src;
  u16* dst;
  int i;
  if (b < 4096){
    src = X; dst = Xb; i = b*256 + threadIdx.x;
  } else {
    const int bb = b - 4096;
    const int seg = bb >> 10;
    src = (seg==0)?w0:(seg==1)?w1:(seg==2)?w2:w3;
    dst = Wb + (size_t)seg*DM*DM;
    i = (bb & 1023)*256 + threadIdx.x;
  }
  const float4 v = *(const float4*)(src + (size_t)i*4);
  ushort4 o;
  o.x = f2b(v.x); o.y = f2b(v.y); o.z = f2b(v.z); o.w = f2b(v.w);
  *(ushort4*)(dst + (size_t)i*4) = o;
}

// ---------------- 128x128-tile LDS-staged GEMM ----------------
#define FRAG(buf, row) (*(const short8*)((buf) + (size_t)(row)*32 + ((g ^ (((row)>>1)&3))*8)))

template<int MODE>
__global__ __launch_bounds__(256) void gemm128(const u16* __restrict__ A,
                                               const u16* __restrict__ W,
                                               u16* __restrict__ Ybf,
                                               float* __restrict__ Yf){
  __shared__ u16 sA0[4096], sB0[4096], sA1[4096], sB1[4096];
  const int tid = threadIdx.x;
  const int lane = tid & 63;
  const int wave = tid >> 6;
  const int r = lane & 15, g = lane >> 4;
  const int wr = wave >> 1, wc = wave & 1;
  const int m0 = blockIdx.y << 7;
  const int nn0 = blockIdx.x << 7;

  const int srow = tid >> 2;
  const int lcol = (((tid & 3) ^ ((srow >> 1) & 3))) * 8;

  const u16* gA0 = A + (size_t)(m0 + srow)*DM + lcol;
  const u16* gA1 = gA0 + (size_t)64*DM;
  const u16* gB0 = W + (size_t)(nn0 + srow)*DM + lcol;
  const u16* gB1 = gB0 + (size_t)64*DM;

  f32x4 acc[4][4];
  #pragma unroll
  for (int i=0;i<4;i++)
    #pragma unroll
    for (int j=0;j<4;j++) acc[i][j] = (f32x4){0.f,0.f,0.f,0.f};

#define STAGE(SA, SB, koff) { \
    gll16(gA0 + (koff), SA + (size_t)tid*8); \
    gll16(gA1 + (koff), SA + 2048 + (size_t)tid*8); \
    gll16(gB0 + (koff), SB + (size_t)tid*8); \
    gll16(gB1 + (koff), SB + 2048 + (size_t)tid*8); }

#define COMPUTE(SA, SB) { \
    short8 af[4], bf[4]; \
    _Pragma("unroll") \
    for (int f=0; f<4; f++){ \
      af[f] = FRAG(SA, wr*64 + f*16 + r); \
      bf[f] = FRAG(SB, wc*64 + f*16 + r); \
    } \
    _Pragma("unroll") \
    for (int fr=0; fr<4; fr++) \
      _Pragma("unroll") \
      for (int fn=0; fn<4; fn++) \
        acc[fr][fn] = __builtin_amdgcn_mfma_f32_16x16x32_bf16(af[fr], bf[fn], acc[fr][fn], 0,0,0); }

  STAGE(sA0, sB0, 0);
  __syncthreads();

  for (int t = 0; t < 32; t += 2){
    if (t + 1 < 32) STAGE(sA1, sB1, (t+1)*32);
    COMPUTE(sA0, sB0);
    __syncthreads();
    if (t + 2 < 32) STAGE(sA0, sB0, (t+2)*32);
    COMPUTE(sA1, sB1);
    __syncthreads();
  }

  #pragma unroll
  for (int fr=0; fr<4; fr++){
    #pragma unroll
    for (int i=0;i<4;i++){
      const int m = m0 + wr*64 + fr*16 + g*4 + i;
      #pragma unroll
      for (int fn=0; fn<4; fn++){
        const int nn = nn0 + wc*64 + fn*16 + r;
        if (MODE == 0){
          Ybf[(size_t)(nn >> 10)*BT*DM + (size_t)m*DM + (nn & 1023)] = f2b(acc[fr][fn][i]);
        } else {
          Yf[(size_t)m*DM + nn] = acc[fr][fn][i];
        }
      }
    }
  }
#undef STAGE
#undef COMPUTE
}

// ---------------- RoPE on Q,K (Q pre-scaled by SC2) ----------------
__global__ __launch_bounds__(256) void rope_kernel(u16* __restrict__ Qb, u16* __restrict__ Kb,
                                                   const int* __restrict__ pos){
  const int t = blockIdx.x*256 + threadIdx.x;
  const int m = t >> 5;
  const int fi = t & 31;
  const float invf = __expf(-(float)fi * 0.28782313662425575f);
  float s, c;
  sincosf((float)pos[m] * invf, &s, &c);
  const float cq = c*SC2, sq = s*SC2;
  const size_t base = (size_t)m*DM + fi*2;
  #pragma unroll
  for (int h=0; h<NH; h++){
    const size_t a = base + h*HD;
    {
      const float x0 = b2f(Qb[a]), x1 = b2f(Qb[a+1]);
      Qb[a]   = f2b(cq*x0 - sq*x1);
      Qb[a+1] = f2b(cq*x1 + sq*x0);
    }
    {
      const float x0 = b2f(Kb[a]), x1 = b2f(Kb[a+1]);
      Kb[a]   = f2b(c*x0 - s*x1);
      Kb[a+1] = f2b(c*x1 + s*x0);
    }
  }
}

// -------- V transpose, key-INTERLEAVED within 32-groups --------
__global__ __launch_bounds__(256) void transpose_v_kernel(const u16* __restrict__ Vb,
                                                          u16* __restrict__ Vt){
  __shared__ u16 tile[64][72];
  const int bh = blockIdx.x >> 5;
  const int sc = blockIdx.x & 31;
  const int bq = bh >> 4, h = bh & 15;
  const int s0 = sc*64;
  {
    const int row = threadIdx.x >> 3;
    const int c8 = (threadIdx.x & 7)*8;
    #pragma unroll
    for (int rr = 0; rr < 64; rr += 32){
      const short8 v = *(const short8*)(Vb + (size_t)(bq*TT + s0 + row + rr)*DM + h*HD + c8);
      *(short8*)(&tile[row+rr][c8]) = v;
    }
  }
  __syncthreads();
  {
    const int d = threadIdx.x >> 3;
    const int s8 = (threadIdx.x & 7)*8;
    #pragma unroll
    for (int dd = 0; dd < 64; dd += 32){
      short8 ov;
      #pragma unroll
      for (int j=0;j<8;j++){
        const int sl = s8 + j;
        const int w = sl & 31;
        const int slog = (sl & 32) + (w >> 1) + ((w & 1) << 4);
        ov[j] = (short)tile[slog][d+dd];
      }
      *(short8*)(Vt + ((size_t)bh*HD + d + dd)*TT + s0 + s8) = ov;
    }
  }
}

// ---------- causal flash attention: 8-wave blocks, parity split-K, m=0 softmax ----------
template<bool MASKED>
__device__ __forceinline__ void proc_fast(
    const short8 qf0, const short8 qf1,
    const short8 k00, const short8 k01, const short8 k10, const short8 k11,
    const short8 v0, const short8 v1, const short8 v2, const short8 v3,
    f32x4& o0, f32x4& o1, f32x4& o2, f32x4& o3,
    float (&lsum)[4],
    const int q0, const int s0, const int r, const int g,
    u16 (*pbuf)[40])
{
  f32x4 sa0={0,0,0,0}, sa1={0,0,0,0};
  __builtin_amdgcn_s_setprio(1);
  sa0 = __builtin_amdgcn_mfma_f32_16x16x32_bf16(qf0, k00, sa0, 0,0,0);
  sa0 = __builtin_amdgcn_mfma_f32_16x16x32_bf16(qf1, k01, sa0, 0,0,0);
  sa1 = __builtin_amdgcn_mfma_f32_16x16x32_bf16(qf0, k10, sa1, 0,0,0);
  sa1 = __builtin_amdgcn_mfma_f32_16x16x32_bf16(qf1, k11, sa1, 0,0,0);
  __builtin_amdgcn_s_setprio(0);
  #pragma unroll
  for (int i=0;i<4;i++){
    float a = sa0[i], b = sa1[i];
    if (MASKED){
      const int q = q0 + g*4 + i;
      a = (s0 + r      <= q) ? a : -3.0e38f;
      b = (s0 + 16 + r <= q) ? b : -3.0e38f;
    }
    const float p0 = exp2f(a);
    const float p1 = exp2f(b);
    lsum[i] += p0 + p1;
    unsigned w;
    asm("v_cvt_pk_bf16_f32 %0, %1, %2" : "=v"(w) : "v"(p0), "v"(p1));
    *(unsigned*)(&pbuf[g*4+i][r*2]) = w;   // keys r (lo half), 16+r (hi half) interleaved
  }
  const short8 pf = *(const short8*)(&pbuf[r][g*8]);
  __builtin_amdgcn_s_setprio(1);
  o0 = __builtin_amdgcn_mfma_f32_16x16x32_bf16(pf, v0, o0, 0,0,0);
  o1 = __builtin_amdgcn_mfma_f32_16x16x32_bf16(pf, v1, o1, 0,0,0);
  o2 = __builtin_amdgcn_mfma_f32_16x16x32_bf16(pf, v2, o2, 0,0,0);
  o3 = __builtin_amdgcn_mfma_f32_16x16x32_bf16(pf, v3, o3, 0,0,0);
  __builtin_amdgcn_s_setprio(0);
}

__global__ __launch_bounds__(512) void attn_kernel(const u16* __restrict__ Qb,
                                                   const u16* __restrict__ Kb,
                                                   const u16* __restrict__ Vt,
                                                   u16* __restrict__ Ob){
  __shared__ u16 KVs[2][8192];       // [buf][ K: 64x64 | V: 64x64 ], slot-swizzled
  __shared__ u16 Plds[8][16][40];
  const int tid = threadIdx.x;
  const int lane = tid & 63;
  const int wave = tid >> 6;         // 0..7
  const int wq = wave & 3;           // q-row group
  const int par = wave >> 2;         // KV-half parity
  const int r = lane & 15, g = lane >> 4;

  const int pp = blockIdx.x;             // 0..15 (panel pair)
  const int bh = blockIdx.y;             // 0..31
  const int bq = bh >> 4, h = bh & 15;
  const int lo = pp, hi = 31 - pp;
  const int w0A = lo*64 + wq*16;
  const int w0B = hi*64 + wq*16;
  const int sAd = (w0A >> 5) << 5;       // diagonal 32-block start for tile A
  const int sBd = (w0B >> 5) << 5;
  const int nb = hi + 1;                 // 64-row KV stage iterations

  // ---- Q fragments (pre-scaled by SC2 in rope) ----
  const u16* QrowA = Qb + (size_t)(bq*TT + w0A + r)*DM + h*HD;
  const u16* QrowB = Qb + (size_t)(bq*TT + w0B + r)*DM + h*HD;
  const short8 qA0 = *(const short8*)(QrowA + g*8);
  const short8 qA1 = *(const short8*)(QrowA + 32 + g*8);
  const short8 qB0 = *(const short8*)(QrowB + g*8);
  const short8 qB1 = *(const short8*)(QrowB + 32 + g*8);

  // ---- staging sources (pre-swizzled): 512 threads, 1 gll16 each for K and V ----
  const int srow = tid >> 3;                      // 0..63
  const int scol = ((tid & 7) ^ (srow & 7)) * 8;
  const u16* Ksrc = Kb + (size_t)(bq*TT + srow)*DM + h*HD + scol;
  const u16* Vsrc = Vt + (size_t)bh*HD*TT + (size_t)srow*TT + scol;

  f32x4 oA0={0,0,0,0}, oA1={0,0,0,0}, oA2={0,0,0,0}, oA3={0,0,0,0};
  f32x4 oB0={0,0,0,0}, oB1={0,0,0,0}, oB2={0,0,0,0}, oB3={0,0,0,0};
  float lA[4] = {0.f,0.f,0.f,0.f}, lB[4] = {0.f,0.f,0.f,0.f};

#define STAGEKV(B, S64) { \
    gll16(Ksrc + (size_t)(S64)*DM, &KVs[B][0]    + (size_t)tid*8); \
    gll16(Vsrc + (S64),            &KVs[B][4096] + (size_t)tid*8); }

  STAGEKV(0, 0);
  __syncthreads();

  for (int ib = 0; ib < nb; ib++){
    const int cur = ib & 1;
    if (ib + 1 < nb) STAGEKV(cur ^ 1, (ib + 1)*64);
    const int s0 = ib*64 + par*32;         // this wave's 32-key half
    if (s0 <= sBd){
      const u16* kb_ = KVs[cur];
      const u16* vb_ = KVs[cur] + 4096;
      const int rb = par*32 + r;
      const int ph0 = (g ^ (r & 7))*8;
      const int ph1 = ((g + 4) ^ (r & 7))*8;
      const short8 k00 = *(const short8*)(kb_ + (size_t)rb*64 + ph0);
      const short8 k01 = *(const short8*)(kb_ + (size_t)rb*64 + ph1);
      const short8 k10 = *(const short8*)(kb_ + (size_t)(rb+16)*64 + ph0);
      const short8 k11 = *(const short8*)(kb_ + (size_t)(rb+16)*64 + ph1);
      const int vc = ((par*4 + g) ^ (r & 7))*8;
      const short8 v0 = *(const short8*)(vb_ + (size_t)(r     )*64 + vc);
      const short8 v1 = *(const short8*)(vb_ + (size_t)(16 + r)*64 + vc);
      const short8 v2 = *(const short8*)(vb_ + (size_t)(32 + r)*64 + vc);
      const short8 v3 = *(const short8*)(vb_ + (size_t)(48 + r)*64 + vc);
      if (s0 <= sAd){
        if (s0 == sAd) proc_fast<true >(qA0,qA1,k00,k01,k10,k11,v0,v1,v2,v3,
                                        oA0,oA1,oA2,oA3,lA,w0A,s0,r,g,Plds[wave]);
        else           proc_fast<false>(qA0,qA1,k00,k01,k10,k11,v0,v1,v2,v3,
                                        oA0,oA1,oA2,oA3,lA,w0A,s0,r,g,Plds[wave]);
      }
      if (s0 == sBd) proc_fast<true >(qB0,qB1,k00,k01,k10,k11,v0,v1,v2,v3,
                                      oB0,oB1,oB2,oB3,lB,w0B,s0,r,g,Plds[wave]);
      else           proc_fast<false>(qB0,qB1,k00,k01,k10,k11,v0,v1,v2,v3,
                                      oB0,oB1,oB2,oB3,lB,w0B,s0,r,g,Plds[wave]);
    }
    __syncthreads();
  }
#undef STAGEKV

  // ---- parity merge (pure sums; m==0 so no max/exp needed) ----
  float* scr = (float*)&KVs[0][0];           // 20 KB scratch per phase (<=32 KB)
  const int mbase = wq*20*64 + lane;
  // phase 1: tile A
  if (par == 1){
    #pragma unroll
    for (int i=0;i<4;i++){
      scr[mbase + (0*4+i)*64] = oA0[i];
      scr[mbase + (1*4+i)*64] = oA1[i];
      scr[mbase + (2*4+i)*64] = oA2[i];
      scr[mbase + (3*4+i)*64] = oA3[i];
      scr[mbase + (16+i)*64]  = lA[i];
    }
  }
  __syncthreads();
  if (par == 0){
    #pragma unroll
    for (int i=0;i<4;i++){
      oA0[i] += scr[mbase + (0*4+i)*64];
      oA1[i] += scr[mbase + (1*4+i)*64];
      oA2[i] += scr[mbase + (2*4+i)*64];
      oA3[i] += scr[mbase + (3*4+i)*64];
      lA[i]  += scr[mbase + (16+i)*64];
    }
  }
  __syncthreads();
  // phase 2: tile B
  if (par == 1){
    #pragma unroll
    for (int i=0;i<4;i++){
      scr[mbase + (0*4+i)*64] = oB0[i];
      scr[mbase + (1*4+i)*64] = oB1[i];
      scr[mbase + (2*4+i)*64] = oB2[i];
      scr[mbase + (3*4+i)*64] = oB3[i];
      scr[mbase + (16+i)*64]  = lB[i];
    }
  }
  __syncthreads();
  if (par == 0){
    #pragma unroll
    for (int i=0;i<4;i++){
      oB0[i] += scr[mbase + (0*4+i)*64];
      oB1[i] += scr[mbase + (1*4+i)*64];
      oB2[i] += scr[mbase + (2*4+i)*64];
      oB3[i] += scr[mbase + (3*4+i)*64];
      lB[i]  += scr[mbase + (16+i)*64];
    }
    // ---- final row-sum reduction (across the 16 key-lanes) + output ----
    #pragma unroll
    for (int off=8; off>0; off>>=1){
      #pragma unroll
      for (int i=0;i<4;i++){
        lA[i] += __shfl_xor(lA[i], off);
        lB[i] += __shfl_xor(lB[i], off);
      }
    }
    float invA[4], invB[4];
    #pragma unroll
    for (int i=0;i<4;i++){ invA[i] = 1.0f/lA[i]; invB[i] = 1.0f/lB[i]; }
    #pragma unroll
    for (int i=0;i<4;i++){
      const size_t rowA = (size_t)(bq*TT + w0A + g*4 + i)*DM + h*HD;
      Ob[rowA + r]      = f2b(oA0[i]*invA[i]);
      Ob[rowA + 16 + r] = f2b(oA1[i]*invA[i]);
      Ob[rowA + 32 + r] = f2b(oA2[i]*invA[i]);
      Ob[rowA + 48 + r] = f2b(oA3[i]*invA[i]);
      const size_t rowB = (size_t)(bq*TT + w0B + g*4 + i)*DM + h*HD;
      Ob[rowB + r]      = f2b(oB0[i]*invB[i]);
      Ob[rowB + 16 + r] = f2b(oB1[i]*invB[i]);
      Ob[rowB + 32 + r] = f2b(oB2[i]*invB[i]);
      Ob[rowB + 48 + r] = f2b(oB3[i]*invB[i]);
    }
  }
}

extern "C" void kernel_launch(void* const* d_in, const int* in_sizes, int n_in,
                              void* d_out, int out_size, void* d_ws, size_t ws_size,
                              hipStream_t stream) {
  const float* X  = (const float*)d_in[0];
  const int* pos  = (const int*)d_in[1];
  const float* Wq = (const float*)d_in[2];
  const float* Wk = (const float*)d_in[3];
  const float* Wv = (const float*)d_in[4];
  const float* Wo = (const float*)d_in[5];
  float* out = (float*)d_out;

  char* ws = (char*)d_ws;
  u16* Xb = (u16*)ws;                                    // 8 MB (reused as Vt later)
  u16* Vt = (u16*)ws;                                    // aliases Xb (dead after QKV gemm)
  u16* Wb = (u16*)(ws + (size_t)8*1024*1024);            // 4 x 2 MB (q,k,v,o)
  u16* Qb = (u16*)(ws + (size_t)16*1024*1024);           // 8 MB
  u16* Kb = Qb + (size_t)BT*DM;                          // 8 MB
  u16* Vb = Kb + (size_t)BT*DM;                          // 8 MB
  u16* Ob = (u16*)(ws + (size_t)40*1024*1024);           // 8 MB

  const int DD = DM*DM;
  cvt_all_kernel<<<8192, 256, 0, stream>>>(X, Wq, Wk, Wv, Wo, Xb, Wb);

  gemm128<0><<<dim3(24, 32), 256, 0, stream>>>(Xb, Wb, Qb, nullptr);
  rope_kernel<<<512, 256, 0, stream>>>(Qb, Kb, pos);
  transpose_v_kernel<<<1024, 256, 0, stream>>>(Vb, Vt);
  attn_kernel<<<dim3(16, 32), 512, 0, stream>>>(Qb, Kb, Vt, Ob);
  gemm128<1><<<dim3(8, 32), 256, 0, stream>>>(Ob, Wb + 3*DD, nullptr, out);
}

// Round 9
// 116.881 us; speedup vs baseline: 2.3365x; 1.0581x over previous
//
#include <hip/hip_runtime.h>
#include <hip/hip_bf16.h>

#define BB 2
#define TT 2048
#define DM 1024
#define NH 16
#define HD 64
#define BT (BB*TT)
#define SC2 0.18033688011112042f   // 0.125 / ln(2)

typedef unsigned short u16;
typedef __attribute__((ext_vector_type(8))) short short8;
typedef __attribute__((ext_vector_type(4))) float f32x4;

__device__ __forceinline__ u16 f2b(float f){
  unsigned u = __builtin_bit_cast(unsigned, f);
  u += 0x7FFFu + ((u >> 16) & 1u);
  return (u16)(u >> 16);
}
__device__ __forceinline__ float b2f(u16 h){
  unsigned u = ((unsigned)h) << 16;
  return __builtin_bit_cast(float, u);
}

__device__ __forceinline__ void gll16(const u16* g, u16* l){
  __builtin_amdgcn_global_load_lds((const __attribute__((address_space(1))) void*)g,
                                   (__attribute__((address_space(3))) void*)l, 16, 0, 0);
}

// ---------------- fused f32 -> bf16 conversion (X + 4 weights) ----------------
__global__ __launch_bounds__(256) void cvt_all_kernel(const float* __restrict__ X,
                                                      const float* __restrict__ w0,
                                                      const float* __restrict__ w1,
                                                      const float* __restrict__ w2,
                                                      const float* __restrict__ w3,
                                                      u16* __restrict__ Xb,
                                                      u16* __restrict__ Wb){
  const int b = blockIdx.x;
  const float* src;
  u16* dst;
  int i;
  if (b < 4096){
    src = X; dst = Xb; i = b*256 + threadIdx.x;
  } else {
    const int bb = b - 4096;
    const int seg = bb >> 10;
    src = (seg==0)?w0:(seg==1)?w1:(seg==2)?w2:w3;
    dst = Wb + (size_t)seg*DM*DM;
    i = (bb & 1023)*256 + threadIdx.x;
  }
  const float4 v = *(const float4*)(src + (size_t)i*4);
  ushort4 o;
  o.x = f2b(v.x); o.y = f2b(v.y); o.z = f2b(v.z); o.w = f2b(v.w);
  *(ushort4*)(dst + (size_t)i*4) = o;
}

// ---------------- 128x128-tile LDS-staged GEMM ----------------
#define FRAG(buf, row) (*(const short8*)((buf) + (size_t)(row)*32 + ((g ^ (((row)>>1)&3))*8)))

template<int MODE>
__global__ __launch_bounds__(256) void gemm128(const u16* __restrict__ A,
                                               const u16* __restrict__ W,
                                               u16* __restrict__ Ybf,
                                               float* __restrict__ Yf){
  __shared__ u16 sA0[4096], sB0[4096], sA1[4096], sB1[4096];
  const int tid = threadIdx.x;
  const int lane = tid & 63;
  const int wave = tid >> 6;
  const int r = lane & 15, g = lane >> 4;
  const int wr = wave >> 1, wc = wave & 1;
  const int m0 = blockIdx.y << 7;
  const int nn0 = blockIdx.x << 7;

  const int srow = tid >> 2;
  const int lcol = (((tid & 3) ^ ((srow >> 1) & 3))) * 8;

  const u16* gA0 = A + (size_t)(m0 + srow)*DM + lcol;
  const u16* gA1 = gA0 + (size_t)64*DM;
  const u16* gB0 = W + (size_t)(nn0 + srow)*DM + lcol;
  const u16* gB1 = gB0 + (size_t)64*DM;

  f32x4 acc[4][4];
  #pragma unroll
  for (int i=0;i<4;i++)
    #pragma unroll
    for (int j=0;j<4;j++) acc[i][j] = (f32x4){0.f,0.f,0.f,0.f};

#define STAGE(SA, SB, koff) { \
    gll16(gA0 + (koff), SA + (size_t)tid*8); \
    gll16(gA1 + (koff), SA + 2048 + (size_t)tid*8); \
    gll16(gB0 + (koff), SB + (size_t)tid*8); \
    gll16(gB1 + (koff), SB + 2048 + (size_t)tid*8); }

#define COMPUTE(SA, SB) { \
    short8 af[4], bf[4]; \
    _Pragma("unroll") \
    for (int f=0; f<4; f++){ \
      af[f] = FRAG(SA, wr*64 + f*16 + r); \
      bf[f] = FRAG(SB, wc*64 + f*16 + r); \
    } \
    _Pragma("unroll") \
    for (int fr=0; fr<4; fr++) \
      _Pragma("unroll") \
      for (int fn=0; fn<4; fn++) \
        acc[fr][fn] = __builtin_amdgcn_mfma_f32_16x16x32_bf16(af[fr], bf[fn], acc[fr][fn], 0,0,0); }

  STAGE(sA0, sB0, 0);
  __syncthreads();

  for (int t = 0; t < 32; t += 2){
    if (t + 1 < 32) STAGE(sA1, sB1, (t+1)*32);
    COMPUTE(sA0, sB0);
    __syncthreads();
    if (t + 2 < 32) STAGE(sA0, sB0, (t+2)*32);
    COMPUTE(sA1, sB1);
    __syncthreads();
  }

  #pragma unroll
  for (int fr=0; fr<4; fr++){
    #pragma unroll
    for (int i=0;i<4;i++){
      const int m = m0 + wr*64 + fr*16 + g*4 + i;
      #pragma unroll
      for (int fn=0; fn<4; fn++){
        const int nn = nn0 + wc*64 + fn*16 + r;
        if (MODE == 0){
          Ybf[(size_t)(nn >> 10)*BT*DM + (size_t)m*DM + (nn & 1023)] = f2b(acc[fr][fn][i]);
        } else {
          Yf[(size_t)m*DM + nn] = acc[fr][fn][i];
        }
      }
    }
  }
#undef STAGE
#undef COMPUTE
}

// ---------------- RoPE on Q,K (Q pre-scaled by SC2) ----------------
__global__ __launch_bounds__(256) void rope_kernel(u16* __restrict__ Qb, u16* __restrict__ Kb,
                                                   const int* __restrict__ pos){
  const int t = blockIdx.x*256 + threadIdx.x;
  const int m = t >> 5;
  const int fi = t & 31;
  const float invf = __expf(-(float)fi * 0.28782313662425575f);
  float s, c;
  sincosf((float)pos[m] * invf, &s, &c);
  const float cq = c*SC2, sq = s*SC2;
  const size_t base = (size_t)m*DM + fi*2;
  #pragma unroll
  for (int h=0; h<NH; h++){
    const size_t a = base + h*HD;
    {
      const float x0 = b2f(Qb[a]), x1 = b2f(Qb[a+1]);
      Qb[a]   = f2b(cq*x0 - sq*x1);
      Qb[a+1] = f2b(cq*x1 + sq*x0);
    }
    {
      const float x0 = b2f(Kb[a]), x1 = b2f(Kb[a+1]);
      Kb[a]   = f2b(c*x0 - s*x1);
      Kb[a+1] = f2b(c*x1 + s*x0);
    }
  }
}

// -------- V transpose, key-INTERLEAVED within 32-groups --------
__global__ __launch_bounds__(256) void transpose_v_kernel(const u16* __restrict__ Vb,
                                                          u16* __restrict__ Vt){
  __shared__ u16 tile[64][72];
  const int bh = blockIdx.x >> 5;
  const int sc = blockIdx.x & 31;
  const int bq = bh >> 4, h = bh & 15;
  const int s0 = sc*64;
  {
    const int row = threadIdx.x >> 3;
    const int c8 = (threadIdx.x & 7)*8;
    #pragma unroll
    for (int rr = 0; rr < 64; rr += 32){
      const short8 v = *(const short8*)(Vb + (size_t)(bq*TT + s0 + row + rr)*DM + h*HD + c8);
      *(short8*)(&tile[row+rr][c8]) = v;
    }
  }
  __syncthreads();
  {
    const int d = threadIdx.x >> 3;
    const int s8 = (threadIdx.x & 7)*8;
    #pragma unroll
    for (int dd = 0; dd < 64; dd += 32){
      short8 ov;
      #pragma unroll
      for (int j=0;j<8;j++){
        const int sl = s8 + j;
        const int w = sl & 31;
        const int slog = (sl & 32) + (w >> 1) + ((w & 1) << 4);
        ov[j] = (short)tile[slog][d+dd];
      }
      *(short8*)(Vt + ((size_t)bh*HD + d + dd)*TT + s0 + s8) = ov;
    }
  }
}

// ---------- causal flash attention: 8-wave blocks, counted-vmcnt pipeline ----------
template<bool MASKED>
__device__ __forceinline__ void proc_fast(
    const short8 qf0, const short8 qf1,
    const short8 k00, const short8 k01, const short8 k10, const short8 k11,
    const short8 v0, const short8 v1, const short8 v2, const short8 v3,
    f32x4& o0, f32x4& o1, f32x4& o2, f32x4& o3,
    float (&lsum)[4],
    const int q0, const int s0, const int r, const int g,
    u16 (*pbuf)[40])
{
  f32x4 sa0={0,0,0,0}, sa1={0,0,0,0};
  __builtin_amdgcn_s_setprio(1);
  sa0 = __builtin_amdgcn_mfma_f32_16x16x32_bf16(qf0, k00, sa0, 0,0,0);
  sa0 = __builtin_amdgcn_mfma_f32_16x16x32_bf16(qf1, k01, sa0, 0,0,0);
  sa1 = __builtin_amdgcn_mfma_f32_16x16x32_bf16(qf0, k10, sa1, 0,0,0);
  sa1 = __builtin_amdgcn_mfma_f32_16x16x32_bf16(qf1, k11, sa1, 0,0,0);
  __builtin_amdgcn_s_setprio(0);
  #pragma unroll
  for (int i=0;i<4;i++){
    float a = sa0[i], b = sa1[i];
    if (MASKED){
      const int q = q0 + g*4 + i;
      a = (s0 + r      <= q) ? a : -3.0e38f;
      b = (s0 + 16 + r <= q) ? b : -3.0e38f;
    }
    const float p0 = exp2f(a);
    const float p1 = exp2f(b);
    lsum[i] += p0 + p1;
    unsigned w;
    asm("v_cvt_pk_bf16_f32 %0, %1, %2" : "=v"(w) : "v"(p0), "v"(p1));
    *(unsigned*)(&pbuf[g*4+i][r*2]) = w;   // keys r (lo half), 16+r (hi half) interleaved
  }
  const short8 pf = *(const short8*)(&pbuf[r][g*8]);
  __builtin_amdgcn_s_setprio(1);
  o0 = __builtin_amdgcn_mfma_f32_16x16x32_bf16(pf, v0, o0, 0,0,0);
  o1 = __builtin_amdgcn_mfma_f32_16x16x32_bf16(pf, v1, o1, 0,0,0);
  o2 = __builtin_amdgcn_mfma_f32_16x16x32_bf16(pf, v2, o2, 0,0,0);
  o3 = __builtin_amdgcn_mfma_f32_16x16x32_bf16(pf, v3, o3, 0,0,0);
  __builtin_amdgcn_s_setprio(0);
}

__global__ __launch_bounds__(512) void attn_kernel(const u16* __restrict__ Qb,
                                                   const u16* __restrict__ Kb,
                                                   const u16* __restrict__ Vt,
                                                   u16* __restrict__ Ob){
  __shared__ u16 KVs[4][8192];       // 4-deep: [buf][ K: 64x64 | V: 64x64 ], slot-swizzled
  __shared__ u16 Plds[8][16][40];
  const int tid = threadIdx.x;
  const int lane = tid & 63;
  const int wave = tid >> 6;         // 0..7
  const int wq = wave & 3;           // q-row group
  const int par = wave >> 2;         // KV-half parity
  const int r = lane & 15, g = lane >> 4;

  const int bh = blockIdx.x;             // 0..31  (fast dim -> XCD L2 locality)
  const int pp = blockIdx.y;             // 0..15  (panel pair)
  const int bq = bh >> 4, h = bh & 15;
  const int lo = pp, hi = 31 - pp;
  const int w0A = lo*64 + wq*16;
  const int w0B = hi*64 + wq*16;
  const int sAd = (w0A >> 5) << 5;       // diagonal 32-block start for tile A
  const int sBd = (w0B >> 5) << 5;
  const int nb = hi + 1;                 // 64-row KV stage iterations (>=17)

  // ---- Q fragments (pre-scaled by SC2 in rope) ----
  const u16* QrowA = Qb + (size_t)(bq*TT + w0A + r)*DM + h*HD;
  const u16* QrowB = Qb + (size_t)(bq*TT + w0B + r)*DM + h*HD;
  const short8 qA0 = *(const short8*)(QrowA + g*8);
  const short8 qA1 = *(const short8*)(QrowA + 32 + g*8);
  const short8 qB0 = *(const short8*)(QrowB + g*8);
  const short8 qB1 = *(const short8*)(QrowB + 32 + g*8);

  // ---- staging sources (pre-swizzled): 512 threads, 1 gll16 each for K and V ----
  const int srow = tid >> 3;                      // 0..63
  const int scol = ((tid & 7) ^ (srow & 7)) * 8;
  const u16* Ksrc = Kb + (size_t)(bq*TT + srow)*DM + h*HD + scol;
  const u16* Vsrc = Vt + (size_t)bh*HD*TT + (size_t)srow*TT + scol;

  f32x4 oA0={0,0,0,0}, oA1={0,0,0,0}, oA2={0,0,0,0}, oA3={0,0,0,0};
  f32x4 oB0={0,0,0,0}, oB1={0,0,0,0}, oB2={0,0,0,0}, oB3={0,0,0,0};
  float lA[4] = {0.f,0.f,0.f,0.f}, lB[4] = {0.f,0.f,0.f,0.f};

#define STAGEKV(B, S64) { \
    gll16(Ksrc + (size_t)(S64)*DM, &KVs[B][0]    + (size_t)tid*8); \
    gll16(Vsrc + (S64),            &KVs[B][4096] + (size_t)tid*8); }

  STAGEKV(0, 0);
  STAGEKV(1, 64);
  asm volatile("" ::: "memory");

  for (int ib = 0; ib < nb; ib++){
    const int cur = ib & 3;
    // prefetch depth 2; counted vmcnt BEFORE the barrier (never drains prefetch)
    if (ib + 2 < nb){
      STAGEKV((ib+2)&3, (ib+2)*64);
      asm volatile("s_waitcnt vmcnt(4)" ::: "memory");
    } else if (ib + 1 < nb){
      asm volatile("s_waitcnt vmcnt(2)" ::: "memory");
    } else {
      asm volatile("s_waitcnt vmcnt(0)" ::: "memory");
    }
    __builtin_amdgcn_s_barrier();

    const int s0 = ib*64 + par*32;         // this wave's 32-key half
    if (s0 <= sBd){
      const u16* kb_ = KVs[cur];
      const u16* vb_ = KVs[cur] + 4096;
      const int rb = par*32 + r;
      const int ph0 = (g ^ (r & 7))*8;
      const int ph1 = ((g + 4) ^ (r & 7))*8;
      const short8 k00 = *(const short8*)(kb_ + (size_t)rb*64 + ph0);
      const short8 k01 = *(const short8*)(kb_ + (size_t)rb*64 + ph1);
      const short8 k10 = *(const short8*)(kb_ + (size_t)(rb+16)*64 + ph0);
      const short8 k11 = *(const short8*)(kb_ + (size_t)(rb+16)*64 + ph1);
      const int vc = ((par*4 + g) ^ (r & 7))*8;
      const short8 v0 = *(const short8*)(vb_ + (size_t)(r     )*64 + vc);
      const short8 v1 = *(const short8*)(vb_ + (size_t)(16 + r)*64 + vc);
      const short8 v2 = *(const short8*)(vb_ + (size_t)(32 + r)*64 + vc);
      const short8 v3 = *(const short8*)(vb_ + (size_t)(48 + r)*64 + vc);
      if (s0 <= sAd){
        if (s0 == sAd) proc_fast<true >(qA0,qA1,k00,k01,k10,k11,v0,v1,v2,v3,
                                        oA0,oA1,oA2,oA3,lA,w0A,s0,r,g,Plds[wave]);
        else           proc_fast<false>(qA0,qA1,k00,k01,k10,k11,v0,v1,v2,v3,
                                        oA0,oA1,oA2,oA3,lA,w0A,s0,r,g,Plds[wave]);
      }
      if (s0 == sBd) proc_fast<true >(qB0,qB1,k00,k01,k10,k11,v0,v1,v2,v3,
                                      oB0,oB1,oB2,oB3,lB,w0B,s0,r,g,Plds[wave]);
      else           proc_fast<false>(qB0,qB1,k00,k01,k10,k11,v0,v1,v2,v3,
                                      oB0,oB1,oB2,oB3,lB,w0B,s0,r,g,Plds[wave]);
    }
  }
#undef STAGEKV

  // ---- parity merge (pure sums; m==0 so no max/exp needed) ----
  __syncthreads();
  float* scr = (float*)&KVs[0][0];           // 20 KB scratch per phase
  const int mbase = wq*20*64 + lane;
  // phase 1: tile A
  if (par == 1){
    #pragma unroll
    for (int i=0;i<4;i++){
      scr[mbase + (0*4+i)*64] = oA0[i];
      scr[mbase + (1*4+i)*64] = oA1[i];
      scr[mbase + (2*4+i)*64] = oA2[i];
      scr[mbase + (3*4+i)*64] = oA3[i];
      scr[mbase + (16+i)*64]  = lA[i];
    }
  }
  __syncthreads();
  if (par == 0){
    #pragma unroll
    for (int i=0;i<4;i++){
      oA0[i] += scr[mbase + (0*4+i)*64];
      oA1[i] += scr[mbase + (1*4+i)*64];
      oA2[i] += scr[mbase + (2*4+i)*64];
      oA3[i] += scr[mbase + (3*4+i)*64];
      lA[i]  += scr[mbase + (16+i)*64];
    }
  }
  __syncthreads();
  // phase 2: tile B
  if (par == 1){
    #pragma unroll
    for (int i=0;i<4;i++){
      scr[mbase + (0*4+i)*64] = oB0[i];
      scr[mbase + (1*4+i)*64] = oB1[i];
      scr[mbase + (2*4+i)*64] = oB2[i];
      scr[mbase + (3*4+i)*64] = oB3[i];
      scr[mbase + (16+i)*64]  = lB[i];
    }
  }
  __syncthreads();
  if (par == 0){
    #pragma unroll
    for (int i=0;i<4;i++){
      oB0[i] += scr[mbase + (0*4+i)*64];
      oB1[i] += scr[mbase + (1*4+i)*64];
      oB2[i] += scr[mbase + (2*4+i)*64];
      oB3[i] += scr[mbase + (3*4+i)*64];
      lB[i]  += scr[mbase + (16+i)*64];
    }
    // ---- final row-sum reduction (across the 16 key-lanes) + output ----
    #pragma unroll
    for (int off=8; off>0; off>>=1){
      #pragma unroll
      for (int i=0;i<4;i++){
        lA[i] += __shfl_xor(lA[i], off);
        lB[i] += __shfl_xor(lB[i], off);
      }
    }
    float invA[4], invB[4];
    #pragma unroll
    for (int i=0;i<4;i++){ invA[i] = 1.0f/lA[i]; invB[i] = 1.0f/lB[i]; }
    #pragma unroll
    for (int i=0;i<4;i++){
      const size_t rowA = (size_t)(bq*TT + w0A + g*4 + i)*DM + h*HD;
      Ob[rowA + r]      = f2b(oA0[i]*invA[i]);
      Ob[rowA + 16 + r] = f2b(oA1[i]*invA[i]);
      Ob[rowA + 32 + r] = f2b(oA2[i]*invA[i]);
      Ob[rowA + 48 + r] = f2b(oA3[i]*invA[i]);
      const size_t rowB = (size_t)(bq*TT + w0B + g*4 + i)*DM + h*HD;
      Ob[rowB + r]      = f2b(oB0[i]*invB[i]);
      Ob[rowB + 16 + r] = f2b(oB1[i]*invB[i]);
      Ob[rowB + 32 + r] = f2b(oB2[i]*invB[i]);
      Ob[rowB + 48 + r] = f2b(oB3[i]*invB[i]);
    }
  }
}

extern "C" void kernel_launch(void* const* d_in, const int* in_sizes, int n_in,
                              void* d_out, int out_size, void* d_ws, size_t ws_size,
                              hipStream_t stream) {
  const float* X  = (const float*)d_in[0];
  const int* pos  = (const int*)d_in[1];
  const float* Wq = (const float*)d_in[2];
  const float* Wk = (const float*)d_in[3];
  const float* Wv = (const float*)d_in[4];
  const float* Wo = (const float*)d_in[5];
  float* out = (float*)d_out;

  char* ws = (char*)d_ws;
  u16* Xb = (u16*)ws;                                    // 8 MB (reused as Vt later)
  u16* Vt = (u16*)ws;                                    // aliases Xb (dead after QKV gemm)
  u16* Wb = (u16*)(ws + (size_t)8*1024*1024);            // 4 x 2 MB (q,k,v,o)
  u16* Qb = (u16*)(ws + (size_t)16*1024*1024);           // 8 MB
  u16* Kb = Qb + (size_t)BT*DM;                          // 8 MB
  u16* Vb = Kb + (size_t)BT*DM;                          // 8 MB
  u16* Ob = (u16*)(ws + (size_t)40*1024*1024);           // 8 MB

  const int DD = DM*DM;
  cvt_all_kernel<<<8192, 256, 0, stream>>>(X, Wq, Wk, Wv, Wo, Xb, Wb);

  gemm128<0><<<dim3(24, 32), 256, 0, stream>>>(Xb, Wb, Qb, nullptr);
  rope_kernel<<<512, 256, 0, stream>>>(Qb, Kb, pos);
  transpose_v_kernel<<<1024, 256, 0, stream>>>(Vb, Vt);
  attn_kernel<<<dim3(32, 16), 512, 0, stream>>>(Qb, Kb, Vt, Ob);
  gemm128<1><<<dim3(8, 32), 256, 0, stream>>>(Ob, Wb + 3*DD, nullptr, out);
}

// Round 10
// 116.016 us; speedup vs baseline: 2.3539x; 1.0075x over previous
//
#include <hip/hip_runtime.h>
#include <hip/hip_bf16.h>

#define BB 2
#define TT 2048
#define DM 1024
#define NH 16
#define HD 64
#define BT (BB*TT)
#define SC2 0.18033688011112042f   // 0.125 / ln(2)

typedef unsigned short u16;
typedef __attribute__((ext_vector_type(8))) short short8;
typedef __attribute__((ext_vector_type(4))) float f32x4;

__device__ __forceinline__ u16 f2b(float f){
  unsigned u = __builtin_bit_cast(unsigned, f);
  u += 0x7FFFu + ((u >> 16) & 1u);
  return (u16)(u >> 16);
}
__device__ __forceinline__ float b2f(u16 h){
  unsigned u = ((unsigned)h) << 16;
  return __builtin_bit_cast(float, u);
}

__device__ __forceinline__ void gll16(const u16* g, u16* l){
  __builtin_amdgcn_global_load_lds((const __attribute__((address_space(1))) void*)g,
                                   (__attribute__((address_space(3))) void*)l, 16, 0, 0);
}

// ---------------- fused f32 -> bf16 conversion (X + 4 weights) ----------------
__global__ __launch_bounds__(256) void cvt_all_kernel(const float* __restrict__ X,
                                                      const float* __restrict__ w0,
                                                      const float* __restrict__ w1,
                                                      const float* __restrict__ w2,
                                                      const float* __restrict__ w3,
                                                      u16* __restrict__ Xb,
                                                      u16* __restrict__ Wb){
  const int b = blockIdx.x;
  const float* src;
  u16* dst;
  int i;
  if (b < 4096){
    src = X; dst = Xb; i = b*256 + threadIdx.x;
  } else {
    const int bb = b - 4096;
    const int seg = bb >> 10;
    src = (seg==0)?w0:(seg==1)?w1:(seg==2)?w2:w3;
    dst = Wb + (size_t)seg*DM*DM;
    i = (bb & 1023)*256 + threadIdx.x;
  }
  const float4 v = *(const float4*)(src + (size_t)i*4);
  ushort4 o;
  o.x = f2b(v.x); o.y = f2b(v.y); o.z = f2b(v.z); o.w = f2b(v.w);
  *(ushort4*)(dst + (size_t)i*4) = o;
}

// ---------------- 128x128-tile LDS-staged GEMM ----------------
#define FRAG(buf, row) (*(const short8*)((buf) + (size_t)(row)*32 + ((g ^ (((row)>>1)&3))*8)))

template<int MODE>
__global__ __launch_bounds__(256) void gemm128(const u16* __restrict__ A,
                                               const u16* __restrict__ W,
                                               u16* __restrict__ Ybf,
                                               float* __restrict__ Yf){
  __shared__ u16 sA0[4096], sB0[4096], sA1[4096], sB1[4096];
  const int tid = threadIdx.x;
  const int lane = tid & 63;
  const int wave = tid >> 6;
  const int r = lane & 15, g = lane >> 4;
  const int wr = wave >> 1, wc = wave & 1;
  const int m0 = blockIdx.y << 7;
  const int nn0 = blockIdx.x << 7;

  const int srow = tid >> 2;
  const int lcol = (((tid & 3) ^ ((srow >> 1) & 3))) * 8;

  const u16* gA0 = A + (size_t)(m0 + srow)*DM + lcol;
  const u16* gA1 = gA0 + (size_t)64*DM;
  const u16* gB0 = W + (size_t)(nn0 + srow)*DM + lcol;
  const u16* gB1 = gB0 + (size_t)64*DM;

  f32x4 acc[4][4];
  #pragma unroll
  for (int i=0;i<4;i++)
    #pragma unroll
    for (int j=0;j<4;j++) acc[i][j] = (f32x4){0.f,0.f,0.f,0.f};

#define STAGE(SA, SB, koff) { \
    gll16(gA0 + (koff), SA + (size_t)tid*8); \
    gll16(gA1 + (koff), SA + 2048 + (size_t)tid*8); \
    gll16(gB0 + (koff), SB + (size_t)tid*8); \
    gll16(gB1 + (koff), SB + 2048 + (size_t)tid*8); }

#define COMPUTE(SA, SB) { \
    short8 af[4], bf[4]; \
    _Pragma("unroll") \
    for (int f=0; f<4; f++){ \
      af[f] = FRAG(SA, wr*64 + f*16 + r); \
      bf[f] = FRAG(SB, wc*64 + f*16 + r); \
    } \
    _Pragma("unroll") \
    for (int fr=0; fr<4; fr++) \
      _Pragma("unroll") \
      for (int fn=0; fn<4; fn++) \
        acc[fr][fn] = __builtin_amdgcn_mfma_f32_16x16x32_bf16(af[fr], bf[fn], acc[fr][fn], 0,0,0); }

  STAGE(sA0, sB0, 0);
  __syncthreads();

  for (int t = 0; t < 32; t += 2){
    if (t + 1 < 32) STAGE(sA1, sB1, (t+1)*32);
    COMPUTE(sA0, sB0);
    __syncthreads();
    if (t + 2 < 32) STAGE(sA0, sB0, (t+2)*32);
    COMPUTE(sA1, sB1);
    __syncthreads();
  }

  #pragma unroll
  for (int fr=0; fr<4; fr++){
    #pragma unroll
    for (int i=0;i<4;i++){
      const int m = m0 + wr*64 + fr*16 + g*4 + i;
      #pragma unroll
      for (int fn=0; fn<4; fn++){
        const int nn = nn0 + wc*64 + fn*16 + r;
        if (MODE == 0){
          Ybf[(size_t)(nn >> 10)*BT*DM + (size_t)m*DM + (nn & 1023)] = f2b(acc[fr][fn][i]);
        } else {
          Yf[(size_t)m*DM + nn] = acc[fr][fn][i];
        }
      }
    }
  }
#undef STAGE
#undef COMPUTE
}

// ------- fused RoPE (blocks 0..511) + V transpose (blocks 512..1535) -------
__global__ __launch_bounds__(256) void rope_vt_kernel(u16* __restrict__ Qb,
                                                      u16* __restrict__ Kb,
                                                      const int* __restrict__ pos,
                                                      const u16* __restrict__ Vb,
                                                      u16* __restrict__ Vt){
  __shared__ u16 tile[64][72];
  if (blockIdx.x < 512){
    // ---- RoPE on Q,K (Q pre-scaled by SC2) ----
    const int t = blockIdx.x*256 + threadIdx.x;
    const int m = t >> 5;
    const int fi = t & 31;
    const float invf = __expf(-(float)fi * 0.28782313662425575f);
    float s, c;
    sincosf((float)pos[m] * invf, &s, &c);
    const float cq = c*SC2, sq = s*SC2;
    const size_t base = (size_t)m*DM + fi*2;
    #pragma unroll
    for (int h=0; h<NH; h++){
      const size_t a = base + h*HD;
      {
        const float x0 = b2f(Qb[a]), x1 = b2f(Qb[a+1]);
        Qb[a]   = f2b(cq*x0 - sq*x1);
        Qb[a+1] = f2b(cq*x1 + sq*x0);
      }
      {
        const float x0 = b2f(Kb[a]), x1 = b2f(Kb[a+1]);
        Kb[a]   = f2b(c*x0 - s*x1);
        Kb[a+1] = f2b(c*x1 + s*x0);
      }
    }
  } else {
    // ---- V transpose, key-INTERLEAVED within 32-groups ----
    const int bidx = blockIdx.x - 512;
    const int bh = bidx >> 5;
    const int sc = bidx & 31;
    const int bq = bh >> 4, h = bh & 15;
    const int s0 = sc*64;
    {
      const int row = threadIdx.x >> 3;
      const int c8 = (threadIdx.x & 7)*8;
      #pragma unroll
      for (int rr = 0; rr < 64; rr += 32){
        const short8 v = *(const short8*)(Vb + (size_t)(bq*TT + s0 + row + rr)*DM + h*HD + c8);
        *(short8*)(&tile[row+rr][c8]) = v;
      }
    }
    __syncthreads();
    {
      const int d = threadIdx.x >> 3;
      const int s8 = (threadIdx.x & 7)*8;
      #pragma unroll
      for (int dd = 0; dd < 64; dd += 32){
        short8 ov;
        #pragma unroll
        for (int j=0;j<8;j++){
          const int sl = s8 + j;
          const int w = sl & 31;
          const int slog = (sl & 32) + (w >> 1) + ((w & 1) << 4);
          ov[j] = (short)tile[slog][d+dd];
        }
        *(short8*)(Vt + ((size_t)bh*HD + d + dd)*TT + s0 + s8) = ov;
      }
    }
  }
}

// ---------- causal flash attention: 8-wave blocks, 2-buf counted-vmcnt, 3 blocks/CU ----------
template<bool MASKED>
__device__ __forceinline__ void proc_fast(
    const short8 qf0, const short8 qf1,
    const short8 k00, const short8 k01, const short8 k10, const short8 k11,
    const short8 v0, const short8 v1, const short8 v2, const short8 v3,
    f32x4& o0, f32x4& o1, f32x4& o2, f32x4& o3,
    float (&lsum)[4],
    const int q0, const int s0, const int r, const int g,
    u16 (*pbuf)[40])
{
  f32x4 sa0={0,0,0,0}, sa1={0,0,0,0};
  __builtin_amdgcn_s_setprio(1);
  sa0 = __builtin_amdgcn_mfma_f32_16x16x32_bf16(qf0, k00, sa0, 0,0,0);
  sa0 = __builtin_amdgcn_mfma_f32_16x16x32_bf16(qf1, k01, sa0, 0,0,0);
  sa1 = __builtin_amdgcn_mfma_f32_16x16x32_bf16(qf0, k10, sa1, 0,0,0);
  sa1 = __builtin_amdgcn_mfma_f32_16x16x32_bf16(qf1, k11, sa1, 0,0,0);
  __builtin_amdgcn_s_setprio(0);
  #pragma unroll
  for (int i=0;i<4;i++){
    float a = sa0[i], b = sa1[i];
    if (MASKED){
      const int q = q0 + g*4 + i;
      a = (s0 + r      <= q) ? a : -3.0e38f;
      b = (s0 + 16 + r <= q) ? b : -3.0e38f;
    }
    const float p0 = exp2f(a);
    const float p1 = exp2f(b);
    lsum[i] += p0 + p1;
    unsigned w;
    asm("v_cvt_pk_bf16_f32 %0, %1, %2" : "=v"(w) : "v"(p0), "v"(p1));
    *(unsigned*)(&pbuf[g*4+i][r*2]) = w;   // keys r (lo half), 16+r (hi half) interleaved
  }
  const short8 pf = *(const short8*)(&pbuf[r][g*8]);
  __builtin_amdgcn_s_setprio(1);
  o0 = __builtin_amdgcn_mfma_f32_16x16x32_bf16(pf, v0, o0, 0,0,0);
  o1 = __builtin_amdgcn_mfma_f32_16x16x32_bf16(pf, v1, o1, 0,0,0);
  o2 = __builtin_amdgcn_mfma_f32_16x16x32_bf16(pf, v2, o2, 0,0,0);
  o3 = __builtin_amdgcn_mfma_f32_16x16x32_bf16(pf, v3, o3, 0,0,0);
  __builtin_amdgcn_s_setprio(0);
}

__global__ __launch_bounds__(512) void attn_kernel(const u16* __restrict__ Qb,
                                                   const u16* __restrict__ Kb,
                                                   const u16* __restrict__ Vt,
                                                   u16* __restrict__ Ob){
  __shared__ u16 KVs[2][8192];       // 2-deep: [buf][ K: 64x64 | V: 64x64 ], slot-swizzled
  __shared__ u16 Plds[8][16][40];
  const int tid = threadIdx.x;
  const int lane = tid & 63;
  const int wave = tid >> 6;         // 0..7
  const int wq = wave & 3;           // q-row group
  const int par = wave >> 2;         // KV-half parity
  const int r = lane & 15, g = lane >> 4;

  const int bh = blockIdx.x;             // 0..31  (fast dim -> XCD L2 locality)
  const int pp = blockIdx.y;             // 0..15  (panel pair)
  const int bq = bh >> 4, h = bh & 15;
  const int lo = pp, hi = 31 - pp;
  const int w0A = lo*64 + wq*16;
  const int w0B = hi*64 + wq*16;
  const int sAd = (w0A >> 5) << 5;       // diagonal 32-block start for tile A
  const int sBd = (w0B >> 5) << 5;
  const int nb = hi + 1;                 // 64-row KV stage iterations (>=17)

  // ---- Q fragments (pre-scaled by SC2 in rope) ----
  const u16* QrowA = Qb + (size_t)(bq*TT + w0A + r)*DM + h*HD;
  const u16* QrowB = Qb + (size_t)(bq*TT + w0B + r)*DM + h*HD;
  const short8 qA0 = *(const short8*)(QrowA + g*8);
  const short8 qA1 = *(const short8*)(QrowA + 32 + g*8);
  const short8 qB0 = *(const short8*)(QrowB + g*8);
  const short8 qB1 = *(const short8*)(QrowB + 32 + g*8);

  // ---- staging sources (pre-swizzled): 512 threads, 1 gll16 each for K and V ----
  const int srow = tid >> 3;                      // 0..63
  const int scol = ((tid & 7) ^ (srow & 7)) * 8;
  const u16* Ksrc = Kb + (size_t)(bq*TT + srow)*DM + h*HD + scol;
  const u16* Vsrc = Vt + (size_t)bh*HD*TT + (size_t)srow*TT + scol;

  f32x4 oA0={0,0,0,0}, oA1={0,0,0,0}, oA2={0,0,0,0}, oA3={0,0,0,0};
  f32x4 oB0={0,0,0,0}, oB1={0,0,0,0}, oB2={0,0,0,0}, oB3={0,0,0,0};
  float lA[4] = {0.f,0.f,0.f,0.f}, lB[4] = {0.f,0.f,0.f,0.f};

#define STAGEKV(B, S64) { \
    gll16(Ksrc + (size_t)(S64)*DM, &KVs[B][0]    + (size_t)tid*8); \
    gll16(Vsrc + (S64),            &KVs[B][4096] + (size_t)tid*8); }

  STAGEKV(0, 0);
  STAGEKV(1, 64);              // nb >= 17 always
  asm volatile("" ::: "memory");

  for (int ib = 0; ib < nb; ib++){
    const int cur = ib & 1;
    // buffer `cur` ready once the 2 oldest loads land; prefetch stays in flight
    if (ib + 1 < nb){
      asm volatile("s_waitcnt vmcnt(2)" ::: "memory");
    } else {
      asm volatile("s_waitcnt vmcnt(0)" ::: "memory");
    }
    __builtin_amdgcn_s_barrier();

    const int s0 = ib*64 + par*32;         // this wave's 32-key half
    if (s0 <= sBd){
      const u16* kb_ = KVs[cur];
      const u16* vb_ = KVs[cur] + 4096;
      const int rb = par*32 + r;
      const int ph0 = (g ^ (r & 7))*8;
      const int ph1 = ((g + 4) ^ (r & 7))*8;
      const short8 k00 = *(const short8*)(kb_ + (size_t)rb*64 + ph0);
      const short8 k01 = *(const short8*)(kb_ + (size_t)rb*64 + ph1);
      const short8 k10 = *(const short8*)(kb_ + (size_t)(rb+16)*64 + ph0);
      const short8 k11 = *(const short8*)(kb_ + (size_t)(rb+16)*64 + ph1);
      const int vc = ((par*4 + g) ^ (r & 7))*8;
      const short8 v0 = *(const short8*)(vb_ + (size_t)(r     )*64 + vc);
      const short8 v1 = *(const short8*)(vb_ + (size_t)(16 + r)*64 + vc);
      const short8 v2 = *(const short8*)(vb_ + (size_t)(32 + r)*64 + vc);
      const short8 v3 = *(const short8*)(vb_ + (size_t)(48 + r)*64 + vc);
      if (s0 <= sAd){
        if (s0 == sAd) proc_fast<true >(qA0,qA1,k00,k01,k10,k11,v0,v1,v2,v3,
                                        oA0,oA1,oA2,oA3,lA,w0A,s0,r,g,Plds[wave]);
        else           proc_fast<false>(qA0,qA1,k00,k01,k10,k11,v0,v1,v2,v3,
                                        oA0,oA1,oA2,oA3,lA,w0A,s0,r,g,Plds[wave]);
      }
      if (s0 == sBd) proc_fast<true >(qB0,qB1,k00,k01,k10,k11,v0,v1,v2,v3,
                                      oB0,oB1,oB2,oB3,lB,w0B,s0,r,g,Plds[wave]);
      else           proc_fast<false>(qB0,qB1,k00,k01,k10,k11,v0,v1,v2,v3,
                                      oB0,oB1,oB2,oB3,lB,w0B,s0,r,g,Plds[wave]);
    }
    // all waves done reading buf `cur` before anyone overwrites it
    __builtin_amdgcn_s_barrier();
    if (ib + 2 < nb) STAGEKV(cur, (ib + 2)*64);
  }
#undef STAGEKV

  // ---- parity merge (pure sums; m==0 so no max/exp needed) ----
  __syncthreads();
  float* scr = (float*)&KVs[0][0];           // 20 KB scratch per phase
  const int mbase = wq*20*64 + lane;
  // phase 1: tile A
  if (par == 1){
    #pragma unroll
    for (int i=0;i<4;i++){
      scr[mbase + (0*4+i)*64] = oA0[i];
      scr[mbase + (1*4+i)*64] = oA1[i];
      scr[mbase + (2*4+i)*64] = oA2[i];
      scr[mbase + (3*4+i)*64] = oA3[i];
      scr[mbase + (16+i)*64]  = lA[i];
    }
  }
  __syncthreads();
  if (par == 0){
    #pragma unroll
    for (int i=0;i<4;i++){
      oA0[i] += scr[mbase + (0*4+i)*64];
      oA1[i] += scr[mbase + (1*4+i)*64];
      oA2[i] += scr[mbase + (2*4+i)*64];
      oA3[i] += scr[mbase + (3*4+i)*64];
      lA[i]  += scr[mbase + (16+i)*64];
    }
  }
  __syncthreads();
  // phase 2: tile B
  if (par == 1){
    #pragma unroll
    for (int i=0;i<4;i++){
      scr[mbase + (0*4+i)*64] = oB0[i];
      scr[mbase + (1*4+i)*64] = oB1[i];
      scr[mbase + (2*4+i)*64] = oB2[i];
      scr[mbase + (3*4+i)*64] = oB3[i];
      scr[mbase + (16+i)*64]  = lB[i];
    }
  }
  __syncthreads();
  if (par == 0){
    #pragma unroll
    for (int i=0;i<4;i++){
      oB0[i] += scr[mbase + (0*4+i)*64];
      oB1[i] += scr[mbase + (1*4+i)*64];
      oB2[i] += scr[mbase + (2*4+i)*64];
      oB3[i] += scr[mbase + (3*4+i)*64];
      lB[i]  += scr[mbase + (16+i)*64];
    }
    // ---- final row-sum reduction (across the 16 key-lanes) + output ----
    #pragma unroll
    for (int off=8; off>0; off>>=1){
      #pragma unroll
      for (int i=0;i<4;i++){
        lA[i] += __shfl_xor(lA[i], off);
        lB[i] += __shfl_xor(lB[i], off);
      }
    }
    float invA[4], invB[4];
    #pragma unroll
    for (int i=0;i<4;i++){ invA[i] = 1.0f/lA[i]; invB[i] = 1.0f/lB[i]; }
    #pragma unroll
    for (int i=0;i<4;i++){
      const size_t rowA = (size_t)(bq*TT + w0A + g*4 + i)*DM + h*HD;
      Ob[rowA + r]      = f2b(oA0[i]*invA[i]);
      Ob[rowA + 16 + r] = f2b(oA1[i]*invA[i]);
      Ob[rowA + 32 + r] = f2b(oA2[i]*invA[i]);
      Ob[rowA + 48 + r] = f2b(oA3[i]*invA[i]);
      const size_t rowB = (size_t)(bq*TT + w0B + g*4 + i)*DM + h*HD;
      Ob[rowB + r]      = f2b(oB0[i]*invB[i]);
      Ob[rowB + 16 + r] = f2b(oB1[i]*invB[i]);
      Ob[rowB + 32 + r] = f2b(oB2[i]*invB[i]);
      Ob[rowB + 48 + r] = f2b(oB3[i]*invB[i]);
    }
  }
}

extern "C" void kernel_launch(void* const* d_in, const int* in_sizes, int n_in,
                              void* d_out, int out_size, void* d_ws, size_t ws_size,
                              hipStream_t stream) {
  const float* X  = (const float*)d_in[0];
  const int* pos  = (const int*)d_in[1];
  const float* Wq = (const float*)d_in[2];
  const float* Wk = (const float*)d_in[3];
  const float* Wv = (const float*)d_in[4];
  const float* Wo = (const float*)d_in[5];
  float* out = (float*)d_out;

  char* ws = (char*)d_ws;
  u16* Xb = (u16*)ws;                                    // 8 MB (reused as Vt later)
  u16* Vt = (u16*)ws;                                    // aliases Xb (dead after QKV gemm)
  u16* Wb = (u16*)(ws + (size_t)8*1024*1024);            // 4 x 2 MB (q,k,v,o)
  u16* Qb = (u16*)(ws + (size_t)16*1024*1024);           // 8 MB
  u16* Kb = Qb + (size_t)BT*DM;                          // 8 MB
  u16* Vb = Kb + (size_t)BT*DM;                          // 8 MB
  u16* Ob = (u16*)(ws + (size_t)40*1024*1024);           // 8 MB

  const int DD = DM*DM;
  cvt_all_kernel<<<8192, 256, 0, stream>>>(X, Wq, Wk, Wv, Wo, Xb, Wb);

  gemm128<0><<<dim3(24, 32), 256, 0, stream>>>(Xb, Wb, Qb, nullptr);
  rope_vt_kernel<<<1536, 256, 0, stream>>>(Qb, Kb, pos, Vb, Vt);
  attn_kernel<<<dim3(32, 16), 512, 0, stream>>>(Qb, Kb, Vt, Ob);
  gemm128<1><<<dim3(8, 32), 256, 0, stream>>>(Ob, Wb + 3*DD, nullptr, out);
}